// Round 1
// baseline (629.864 us; speedup 1.0000x reference)
//
#include <hip/hip_runtime.h>
#include <math.h>

#define BB 8
#define HH 64
#define WWD 64
#define NN (HH*WWD)        // 4096
#define BN (BB*NN)         // 32768
#define TP 64              // positions per block for GEMM kernels

// ---------- helpers ----------
struct F16v { float4 a, b, c, d; };
__device__ inline F16v load16(const float* p) {
    const float4* p4 = (const float4*)p;
    F16v r; r.a = p4[0]; r.b = p4[1]; r.c = p4[2]; r.d = p4[3]; return r;
}
__device__ inline float dot16(const F16v& x, const F16v& y) {
    return x.a.x*y.a.x + x.a.y*y.a.y + x.a.z*y.a.z + x.a.w*y.a.w
         + x.b.x*y.b.x + x.b.y*y.b.y + x.b.z*y.b.z + x.b.w*y.b.w
         + x.c.x*y.c.x + x.c.y*y.c.y + x.c.z*y.c.z + x.c.w*y.c.w
         + x.d.x*y.d.x + x.d.y*y.d.y + x.d.z*y.d.z + x.d.w*y.d.w;
}
__device__ inline void fma16(F16v& o, float w, const F16v& v) {
    o.a.x += w*v.a.x; o.a.y += w*v.a.y; o.a.z += w*v.a.z; o.a.w += w*v.a.w;
    o.b.x += w*v.b.x; o.b.y += w*v.b.y; o.b.z += w*v.b.z; o.b.w += w*v.b.w;
    o.c.x += w*v.c.x; o.c.y += w*v.c.y; o.c.z += w*v.c.z; o.c.w += w*v.c.w;
    o.d.x += w*v.d.x; o.d.y += w*v.d.y; o.d.z += w*v.d.z; o.d.w += w*v.d.w;
}

// ---------- K1: transpose + LayerNorm1 + QKV GEMM ----------
__global__ __launch_bounds__(256) void k1_ln_qkv(
    const float* __restrict__ x, const float* __restrict__ g1, const float* __restrict__ b1,
    const float* __restrict__ Wqkv, const float* __restrict__ bqkv,
    float* __restrict__ xh, float* __restrict__ qkv)
{
    __shared__ __align__(16) float xs[96][68];   // [channel][pos], stride 68 for float4 align
    __shared__ float wt[96][97];                 // [out_chan][in_chan]
    const int tid = threadIdx.x;
    const long bn0 = (long)blockIdx.x * TP;
    const int b = (int)(bn0 >> 12);
    const int hw0 = (int)(bn0 & 4095);
    const float* xb = x + ((long)b * 96 * NN + hw0);

    // stage x tile: [96 channels][64 positions], coalesced reads
    for (int i = 0; i < (96 * TP) / 256; ++i) {
        int idx = i * 256 + tid;
        int c = idx >> 6, p = idx & 63;
        xs[c][p] = xb[(long)c * NN + p];
    }
    __syncthreads();
    // write xh (channels-last), coalesced
    for (int i = 0; i < (96 * TP) / 256; ++i) {
        int idx = i * 256 + tid;
        int p = idx / 96, c = idx - p * 96;
        xh[(bn0 + p) * 96 + c] = xs[c][p];
    }
    __syncthreads();
    // LayerNorm: 4 threads per position
    {
        int p = tid >> 2, part = tid & 3, c0 = part * 24;
        float s = 0.f, ss = 0.f;
        for (int c = c0; c < c0 + 24; ++c) { float v = xs[c][p]; s += v; ss += v * v; }
        s += __shfl_xor(s, 1);  s += __shfl_xor(s, 2);
        ss += __shfl_xor(ss, 1); ss += __shfl_xor(ss, 2);
        float m = s * (1.f / 96.f);
        float rstd = rsqrtf(ss * (1.f / 96.f) - m * m + 1e-5f);
        for (int c = c0; c < c0 + 24; ++c)
            xs[c][p] = (xs[c][p] - m) * rstd * g1[c] + b1[c];
    }
    // QKV GEMM: 3 chunks of 96 output channels
    const int tx = tid & 15, ty = tid >> 4;
    for (int ch = 0; ch < 3; ++ch) {
        __syncthreads();
        for (int i = 0; i < (96 * 96) / 256; ++i) {
            int idx = i * 256 + tid;
            int o = idx / 96, c = idx - o * 96;
            wt[o][c] = Wqkv[(ch * 96 + o) * 96 + c];
        }
        __syncthreads();
        float acc[4][6];
        #pragma unroll
        for (int i2 = 0; i2 < 4; ++i2)
            #pragma unroll
            for (int j = 0; j < 6; ++j) acc[i2][j] = 0.f;
        for (int c = 0; c < 96; ++c) {
            float4 xv = *(const float4*)&xs[c][tx * 4];
            float wv[6];
            #pragma unroll
            for (int j = 0; j < 6; ++j) wv[j] = wt[ty * 6 + j][c];
            #pragma unroll
            for (int j = 0; j < 6; ++j) {
                acc[0][j] += xv.x * wv[j];
                acc[1][j] += xv.y * wv[j];
                acc[2][j] += xv.z * wv[j];
                acc[3][j] += xv.w * wv[j];
            }
        }
        #pragma unroll
        for (int i2 = 0; i2 < 4; ++i2) {
            int p = tx * 4 + i2;
            long base = (bn0 + p) * 288 + ch * 96 + ty * 6;
            #pragma unroll
            for (int j = 0; j < 6; ++j)
                qkv[base + j] = acc[i2][j] + bqkv[ch * 96 + ty * 6 + j];
        }
    }
}

// ---------- K2: multi-dilate local attention ----------
__global__ __launch_bounds__(256) void k2_attn(
    const float* __restrict__ qkv, float* __restrict__ ab)
{
    int t = blockIdx.x * 256 + threadIdx.x;  // BN*6 items
    int n = t & 4095;
    int r = t >> 12;
    int head = r & 1; r >>= 1;
    int di = r % 3, b = r / 3;
    int h = n >> 6, w = n & 63;
    int dil = di + 1;
    int coff = di * 32 + head * 16;
    long nb = ((long)(b << 12) + n);

    F16v q = load16(qkv + nb * 288 + coff);
    float logits[9];
    #pragma unroll
    for (int ki = 0; ki < 3; ++ki)
        #pragma unroll
        for (int kj = 0; kj < 3; ++kj) {
            int hh = h + (ki - 1) * dil, ww = w + (kj - 1) * dil;
            float l = 0.f;
            if ((unsigned)hh < 64u && (unsigned)ww < 64u) {
                F16v kv = load16(qkv + ((long)(b << 12) + (hh << 6) + ww) * 288 + 96 + coff);
                l = dot16(q, kv);
            }
            logits[ki * 3 + kj] = l * 0.25f;   // scale = head_dim^-0.5 = 0.25
        }
    float m = logits[0];
    #pragma unroll
    for (int k = 1; k < 9; ++k) m = fmaxf(m, logits[k]);
    float e[9], s = 0.f;
    #pragma unroll
    for (int k = 0; k < 9; ++k) { e[k] = __expf(logits[k] - m); s += e[k]; }
    // use precise expf for safety
    s = 0.f;
    #pragma unroll
    for (int k = 0; k < 9; ++k) { e[k] = expf(logits[k] - m); s += e[k]; }
    float inv = 1.f / s;
    F16v o; o.a = make_float4(0,0,0,0); o.b = o.a; o.c = o.a; o.d = o.a;
    #pragma unroll
    for (int ki = 0; ki < 3; ++ki)
        #pragma unroll
        for (int kj = 0; kj < 3; ++kj) {
            int hh = h + (ki - 1) * dil, ww = w + (kj - 1) * dil;
            if ((unsigned)hh < 64u && (unsigned)ww < 64u) {
                F16v vv = load16(qkv + ((long)(b << 12) + (hh << 6) + ww) * 288 + 192 + coff);
                fma16(o, e[ki * 3 + kj] * inv, vv);
            }
        }
    float4* op = (float4*)(ab + nb * 96 + coff);
    op[0] = o.a; op[1] = o.b; op[2] = o.c; op[3] = o.d;
}

// ---------- K3: proj GEMM + residual + LayerNorm2 ----------
__global__ __launch_bounds__(256) void k3_proj_ln(
    const float* __restrict__ ab, const float* __restrict__ Wproj, const float* __restrict__ bproj,
    const float* __restrict__ g2, const float* __restrict__ b2,
    float* __restrict__ xh, float* __restrict__ z)
{
    __shared__ __align__(16) float as_[96][68];
    __shared__ float wt[96][97];
    const int tid = threadIdx.x;
    const long bn0 = (long)blockIdx.x * TP;

    for (int i = 0; i < (96 * TP) / 256; ++i) {
        int idx = i * 256 + tid;
        int p = idx / 96, c = idx - p * 96;
        as_[c][p] = ab[(bn0 + p) * 96 + c];
    }
    for (int i = 0; i < (96 * 96) / 256; ++i) {
        int idx = i * 256 + tid;
        int o = idx / 96, c = idx - o * 96;
        wt[o][c] = Wproj[o * 96 + c];
    }
    __syncthreads();
    const int tx = tid & 15, ty = tid >> 4;
    float acc[4][6];
    #pragma unroll
    for (int i2 = 0; i2 < 4; ++i2)
        #pragma unroll
        for (int j = 0; j < 6; ++j) acc[i2][j] = 0.f;
    for (int c = 0; c < 96; ++c) {
        float4 xv = *(const float4*)&as_[c][tx * 4];
        float wv[6];
        #pragma unroll
        for (int j = 0; j < 6; ++j) wv[j] = wt[ty * 6 + j][c];
        #pragma unroll
        for (int j = 0; j < 6; ++j) {
            acc[0][j] += xv.x * wv[j];
            acc[1][j] += xv.y * wv[j];
            acc[2][j] += xv.z * wv[j];
            acc[3][j] += xv.w * wv[j];
        }
    }
    __syncthreads();
    // os (= wt region): xh' = xh + proj(a)
    #pragma unroll
    for (int i2 = 0; i2 < 4; ++i2) {
        int p = tx * 4 + i2;
        #pragma unroll
        for (int j = 0; j < 6; ++j) {
            int oc = ty * 6 + j;
            wt[oc][p] = acc[i2][j] + bproj[oc] + xh[(bn0 + p) * 96 + oc];
        }
    }
    __syncthreads();
    // write xh' back (coalesced)
    for (int i = 0; i < (96 * TP) / 256; ++i) {
        int idx = i * 256 + tid;
        int p = idx / 96, c = idx - p * 96;
        xh[(bn0 + p) * 96 + c] = wt[c][p];
    }
    // LayerNorm2 -> z
    {
        int p = tid >> 2, part = tid & 3, c0 = part * 24;
        float s = 0.f, ss = 0.f;
        for (int c = c0; c < c0 + 24; ++c) { float v = wt[c][p]; s += v; ss += v * v; }
        s += __shfl_xor(s, 1);  s += __shfl_xor(s, 2);
        ss += __shfl_xor(ss, 1); ss += __shfl_xor(ss, 2);
        float m = s * (1.f / 96.f);
        float rstd = rsqrtf(ss * (1.f / 96.f) - m * m + 1e-5f);
        for (int c = c0; c < c0 + 24; ++c)
            z[(bn0 + p) * 96 + c] = (wt[c][p] - m) * rstd * g2[c] + b2[c];
    }
}

// ---------- K4: MLP fc1 + exact GELU ----------
__global__ __launch_bounds__(256) void k4_mlp1(
    const float* __restrict__ z, const float* __restrict__ W1, const float* __restrict__ bm1,
    float* __restrict__ hb)
{
    __shared__ __align__(16) float zs[96][68];
    __shared__ float wt[96][97];
    const int tid = threadIdx.x;
    const long bn0 = (long)blockIdx.x * TP;
    const int ch = blockIdx.y;   // 0..3 -> out channels ch*96..ch*96+95

    for (int i = 0; i < (96 * TP) / 256; ++i) {
        int idx = i * 256 + tid;
        int p = idx / 96, c = idx - p * 96;
        zs[c][p] = z[(bn0 + p) * 96 + c];
    }
    for (int i = 0; i < (96 * 96) / 256; ++i) {
        int idx = i * 256 + tid;
        int o = idx / 96, c = idx - o * 96;
        wt[o][c] = W1[(ch * 96 + o) * 96 + c];
    }
    __syncthreads();
    const int tx = tid & 15, ty = tid >> 4;
    float acc[4][6];
    #pragma unroll
    for (int i2 = 0; i2 < 4; ++i2)
        #pragma unroll
        for (int j = 0; j < 6; ++j) acc[i2][j] = 0.f;
    for (int c = 0; c < 96; ++c) {
        float4 xv = *(const float4*)&zs[c][tx * 4];
        float wv[6];
        #pragma unroll
        for (int j = 0; j < 6; ++j) wv[j] = wt[ty * 6 + j][c];
        #pragma unroll
        for (int j = 0; j < 6; ++j) {
            acc[0][j] += xv.x * wv[j];
            acc[1][j] += xv.y * wv[j];
            acc[2][j] += xv.z * wv[j];
            acc[3][j] += xv.w * wv[j];
        }
    }
    #pragma unroll
    for (int i2 = 0; i2 < 4; ++i2) {
        int p = tx * 4 + i2;
        long base = (bn0 + p) * 384 + ch * 96 + ty * 6;
        #pragma unroll
        for (int j = 0; j < 6; ++j) {
            float v = acc[i2][j] + bm1[ch * 96 + ty * 6 + j];
            hb[base + j] = 0.5f * v * (1.f + erff(v * 0.70710678118654752f));
        }
    }
}

// ---------- K5: MLP fc2 + residual + ReLU + L2 normalize (dim=C) ----------
__global__ __launch_bounds__(256) void k5_mlp2_norm(
    const float* __restrict__ hb, const float* __restrict__ W2, const float* __restrict__ bm2,
    const float* __restrict__ xh, float* __restrict__ xcn)
{
    __shared__ __align__(16) float hs[96][68];
    __shared__ float wt[96][97];
    const int tid = threadIdx.x;
    const long bn0 = (long)blockIdx.x * TP;
    const int tx = tid & 15, ty = tid >> 4;
    float acc[4][6];
    #pragma unroll
    for (int i2 = 0; i2 < 4; ++i2)
        #pragma unroll
        for (int j = 0; j < 6; ++j) acc[i2][j] = 0.f;

    for (int kc = 0; kc < 4; ++kc) {
        __syncthreads();
        for (int i = 0; i < (96 * TP) / 256; ++i) {
            int idx = i * 256 + tid;
            int p = idx / 96, c = idx - p * 96;
            hs[c][p] = hb[(bn0 + p) * 384 + kc * 96 + c];
        }
        for (int i = 0; i < (96 * 96) / 256; ++i) {
            int idx = i * 256 + tid;
            int o = idx / 96, c = idx - o * 96;
            wt[o][c] = W2[o * 384 + kc * 96 + c];
        }
        __syncthreads();
        for (int c = 0; c < 96; ++c) {
            float4 xv = *(const float4*)&hs[c][tx * 4];
            float wv[6];
            #pragma unroll
            for (int j = 0; j < 6; ++j) wv[j] = wt[ty * 6 + j][c];
            #pragma unroll
            for (int j = 0; j < 6; ++j) {
                acc[0][j] += xv.x * wv[j];
                acc[1][j] += xv.y * wv[j];
                acc[2][j] += xv.z * wv[j];
                acc[3][j] += xv.w * wv[j];
            }
        }
    }
    __syncthreads();
    #pragma unroll
    for (int i2 = 0; i2 < 4; ++i2) {
        int p = tx * 4 + i2;
        #pragma unroll
        for (int j = 0; j < 6; ++j) {
            int oc = ty * 6 + j;
            float v = acc[i2][j] + bm2[oc] + xh[(bn0 + p) * 96 + oc];
            wt[oc][p] = fmaxf(v, 0.f);   // relu
        }
    }
    __syncthreads();
    {
        int p = tid >> 2, part = tid & 3, c0 = part * 24;
        float ss = 0.f;
        for (int c = c0; c < c0 + 24; ++c) { float v = wt[c][p]; ss += v * v; }
        ss += __shfl_xor(ss, 1); ss += __shfl_xor(ss, 2);
        float inv = 1.f / fmaxf(sqrtf(ss), 1e-12f);
        for (int c = c0; c < c0 + 24; ++c)
            xcn[(bn0 + p) * 96 + c] = wt[c][p] * inv;
    }
}

// ---------- K6: 5x5 self-correlation ----------
__global__ __launch_bounds__(256) void k6_selfcorr(
    const float* __restrict__ xcn, float* __restrict__ out)
{
    __shared__ float xt[5 * 20 * 97];   // [(row)*20 + col][96 chan], stride 97
    const int tid = threadIdx.x;
    const int wc = blockIdx.x;   // 0..3 (w chunk of 16)
    const int h  = blockIdx.y;   // 0..63
    const int b  = blockIdx.z;   // 0..7
    const int w0 = wc * 16;

    for (int i = 0; i < 38; ++i) {
        int idx = i * 256 + tid;
        if (idx < 9600) {
            int r = idx / (20 * 96);
            int rem = idx - r * (20 * 96);
            int wi = rem / 96, c = rem - wi * 96;
            int hh = h + r - 2, ww = w0 + wi - 2;
            float v = 0.f;
            if ((unsigned)hh < 64u && (unsigned)ww < 64u)
                v = xcn[(((long)b << 12) + (hh << 6) + ww) * 96 + c];
            xt[(r * 20 + wi) * 97 + c] = v;
        }
    }
    __syncthreads();
    const long obase = ((long)b * 96 * 4096 + (long)h * 64) * 25;
    for (int i = 0; i < 150; ++i) {
        int o = i * 256 + tid;          // 96*16*25 = 38400
        int c = o / 400;
        int r2 = o - c * 400;
        int lw = r2 / 25, k = r2 - lw * 25;
        int ki = k / 5, kj = k - ki * 5;
        float center = xt[(2 * 20 + lw + 2) * 97 + c];
        float neigh  = xt[(ki * 20 + lw + kj) * 97 + c];
        out[obase + (long)c * (4096 * 25) + (w0 + lw) * 25 + k] = center * neigh;
    }
}

// ---------- launcher ----------
extern "C" void kernel_launch(void* const* d_in, const int* in_sizes, int n_in,
                              void* d_out, int out_size, void* d_ws, size_t ws_size,
                              hipStream_t stream)
{
    const float* x     = (const float*)d_in[0];
    const float* g1    = (const float*)d_in[1];
    const float* b1    = (const float*)d_in[2];
    const float* Wqkv  = (const float*)d_in[3];
    const float* bqkv  = (const float*)d_in[4];
    const float* Wproj = (const float*)d_in[5];
    const float* bproj = (const float*)d_in[6];
    const float* g2    = (const float*)d_in[7];
    const float* b2    = (const float*)d_in[8];
    const float* W1    = (const float*)d_in[9];
    const float* bm1   = (const float*)d_in[10];
    const float* W2    = (const float*)d_in[11];
    const float* bm2   = (const float*)d_in[12];
    float* out = (float*)d_out;
    float* ws  = (float*)d_ws;

    float* xh  = ws;                          // BN*96
    float* qkv = xh  + (size_t)BN * 96;       // BN*288
    float* ab  = qkv + (size_t)BN * 288;      // BN*96
    float* hb  = ab  + (size_t)BN * 96;       // BN*384
    float* zb  = qkv;                         // reuse (qkv dead after K2)
    float* xcn = ab;                          // reuse (a dead after K3)

    k1_ln_qkv   <<<BN / TP, 256, 0, stream>>>(x, g1, b1, Wqkv, bqkv, xh, qkv);
    k2_attn     <<<(BN * 6) / 256, 256, 0, stream>>>(qkv, ab);
    k3_proj_ln  <<<BN / TP, 256, 0, stream>>>(ab, Wproj, bproj, g2, b2, xh, zb);
    k4_mlp1     <<<dim3(BN / TP, 4), 256, 0, stream>>>(zb, W1, bm1, hb);
    k5_mlp2_norm<<<BN / TP, 256, 0, stream>>>(hb, W2, bm2, xh, xcn);
    k6_selfcorr <<<dim3(4, 64, 8), 256, 0, stream>>>(xcn, out);
}

// Round 2
// 492.813 us; speedup vs baseline: 1.2781x; 1.2781x over previous
//
#include <hip/hip_runtime.h>
#include <math.h>

#define NN 4096            // H*W
#define BN 32768           // B*H*W

using short8 = __attribute__((ext_vector_type(8))) short;
using f32x4  = __attribute__((ext_vector_type(4))) float;
typedef unsigned short ushort_t;

__device__ inline ushort_t f2bf(float f) {
    unsigned u = __builtin_bit_cast(unsigned, f);
    u += 0x7FFFu + ((u >> 16) & 1u);        // RNE
    return (ushort_t)(u >> 16);
}
__device__ inline float bf2f(ushort_t h) {
    unsigned u = ((unsigned)h) << 16;
    return __builtin_bit_cast(float, u);
}

// ============ K1: transpose + LN1 + QKV (MFMA) ============
// x channel-major fp32 -> xh position-major fp32, qkvt channel-major bf16
__global__ __launch_bounds__(256) void k1_ln_qkv(
    const float* __restrict__ x, const float* __restrict__ g1, const float* __restrict__ b1,
    const float* __restrict__ Wqkv, const float* __restrict__ bqkv,
    float* __restrict__ xh, ushort_t* __restrict__ qkvt)
{
    __shared__ __align__(16) float    Cs[96 * 69];       // x tile / LN / result scratch
    __shared__ __align__(16) ushort_t As[64 * 104];      // A frags bf16 [pos][chan]
    __shared__ __align__(16) ushort_t Bs[96 * 104];      // B frags bf16 [out][chan]
    const int tid = threadIdx.x;
    const long bn0 = (long)blockIdx.x * 64;
    const int b = (int)(bn0 >> 12);
    const int hw0 = (int)(bn0 & 4095);
    const float* xb = x + ((long)b * 96 * NN + hw0);

    // stage x tile [c][p], coalesced
    for (int i = 0; i < 24; ++i) {
        int idx = i * 256 + tid;
        int c = idx >> 6, p = idx & 63;
        Cs[c * 69 + p] = xb[(long)c * NN + p];
    }
    __syncthreads();
    // write xh position-major (residual copy of raw x), float4 coalesced
    for (int i = 0; i < 6; ++i) {
        int idx = i * 256 + tid;
        int p = idx / 24, c4 = idx % 24;
        float4 v = make_float4(Cs[(4*c4+0)*69 + p], Cs[(4*c4+1)*69 + p],
                               Cs[(4*c4+2)*69 + p], Cs[(4*c4+3)*69 + p]);
        *(float4*)&xh[(bn0 + p) * 96 + 4*c4] = v;
    }
    __syncthreads();
    // LayerNorm in place: 4 threads per position
    {
        int p = tid >> 2, part = tid & 3, c0 = part * 24;
        float s = 0.f, ss = 0.f;
        for (int c = c0; c < c0 + 24; ++c) { float v = Cs[c*69 + p]; s += v; ss += v*v; }
        s  += __shfl_xor(s, 1);  s  += __shfl_xor(s, 2);
        ss += __shfl_xor(ss, 1); ss += __shfl_xor(ss, 2);
        float m = s * (1.f/96.f);
        float rstd = rsqrtf(ss * (1.f/96.f) - m*m + 1e-5f);
        for (int c = c0; c < c0 + 24; ++c)
            Cs[c*69 + p] = (Cs[c*69 + p] - m) * rstd * g1[c] + b1[c];
    }
    __syncthreads();
    // transpose-convert -> As bf16 [p][c]
    for (int i = 0; i < 12; ++i) {
        int idx = i * 256 + tid;
        int p = idx / 48, cp = idx % 48;
        unsigned lo = f2bf(Cs[(2*cp  )*69 + p]);
        unsigned hi = f2bf(Cs[(2*cp+1)*69 + p]);
        *(unsigned*)&As[p * 104 + 2*cp] = lo | (hi << 16);
    }

    const int lane = tid & 63, wv = tid >> 6;
    const int ln = lane & 15, qd = lane >> 4;
    for (int ch = 0; ch < 3; ++ch) {
        __syncthreads();
        for (int i = 0; i < 18; ++i) {        // stage weight chunk bf16 [o][c]
            int idx = i * 256 + tid;
            int o = idx / 48, cp = idx % 48;
            const float* wp = Wqkv + (long)(ch*96 + o)*96 + 2*cp;
            unsigned lo = f2bf(wp[0]), hi = f2bf(wp[1]);
            *(unsigned*)&Bs[o * 104 + 2*cp] = lo | (hi << 16);
        }
        __syncthreads();
        f32x4 acc[6];
        #pragma unroll
        for (int t = 0; t < 6; ++t) acc[t] = (f32x4){0.f, 0.f, 0.f, 0.f};
        #pragma unroll
        for (int kc = 0; kc < 3; ++kc) {
            short8 a = *(const short8*)&As[(wv*16 + ln)*104 + kc*32 + qd*8];
            #pragma unroll
            for (int t = 0; t < 6; ++t) {
                short8 bf = *(const short8*)&Bs[(t*16 + ln)*104 + kc*32 + qd*8];
                acc[t] = __builtin_amdgcn_mfma_f32_16x16x32_bf16(a, bf, acc[t], 0, 0, 0);
            }
        }
        // acc -> Cs[outchan][pos]
        #pragma unroll
        for (int t = 0; t < 6; ++t)
            #pragma unroll
            for (int r = 0; r < 4; ++r)
                Cs[(t*16 + ln)*69 + (wv*16 + qd*4 + r)] = acc[t][r];
        __syncthreads();
        // epilogue: +bias, store qkvt channel-major bf16 (pairs of positions)
        for (int i = 0; i < 12; ++i) {
            int idx = i * 256 + tid;
            int c = idx / 32, ph = idx % 32;
            float bias = bqkv[ch*96 + c];
            unsigned lo = f2bf(Cs[c*69 + 2*ph    ] + bias);
            unsigned hi = f2bf(Cs[c*69 + 2*ph + 1] + bias);
            *(unsigned*)&qkvt[(((long)(b*288 + ch*96 + c)) << 12) + hw0 + 2*ph] = lo | (hi << 16);
        }
    }
}

// ============ K2: multi-dilate local attention (channel-major bf16) ============
__global__ __launch_bounds__(256) void k2_attn(
    const ushort_t* __restrict__ qkvt, ushort_t* __restrict__ abt)
{
    int t = blockIdx.x * 256 + threadIdx.x;   // BN*6
    int n = t & 4095;
    int r = t >> 12;                          // 48 combos
    int head = r & 1;
    int di = (r >> 1) % 3;
    int b = r / 6;
    int h = n >> 6, w = n & 63;
    int dil = di + 1;
    const int cg = di*32 + head*16;
    const long planeQ = ((long)(b*288 +       cg)) << 12;
    const long planeK = ((long)(b*288 +  96 + cg)) << 12;
    const long planeV = ((long)(b*288 + 192 + cg)) << 12;

    float q[16];
    #pragma unroll
    for (int d = 0; d < 16; ++d) q[d] = bf2f(qkvt[planeQ + ((long)d << 12) + n]);

    float logits[9];
    #pragma unroll
    for (int ki = 0; ki < 3; ++ki)
        #pragma unroll
        for (int kj = 0; kj < 3; ++kj) {
            int hh = h + (ki-1)*dil, ww = w + (kj-1)*dil;
            float l = 0.f;
            if ((unsigned)hh < 64u && (unsigned)ww < 64u) {
                int nn = (hh << 6) + ww;
                #pragma unroll
                for (int d = 0; d < 16; ++d)
                    l += q[d] * bf2f(qkvt[planeK + ((long)d << 12) + nn]);
            }
            logits[ki*3 + kj] = l * 0.25f;
        }
    float m = logits[0];
    #pragma unroll
    for (int k = 1; k < 9; ++k) m = fmaxf(m, logits[k]);
    float e[9], s = 0.f;
    #pragma unroll
    for (int k = 0; k < 9; ++k) { e[k] = expf(logits[k] - m); s += e[k]; }
    float inv = 1.f / s;

    float o[16];
    #pragma unroll
    for (int d = 0; d < 16; ++d) o[d] = 0.f;
    #pragma unroll
    for (int ki = 0; ki < 3; ++ki)
        #pragma unroll
        for (int kj = 0; kj < 3; ++kj) {
            int hh = h + (ki-1)*dil, ww = w + (kj-1)*dil;
            if ((unsigned)hh < 64u && (unsigned)ww < 64u) {
                int nn = (hh << 6) + ww;
                float wgt = e[ki*3 + kj] * inv;
                #pragma unroll
                for (int d = 0; d < 16; ++d)
                    o[d] += wgt * bf2f(qkvt[planeV + ((long)d << 12) + nn]);
            }
        }
    const long ob = ((long)(b*96 + cg)) << 12;
    #pragma unroll
    for (int d = 0; d < 16; ++d)
        abt[ob + ((long)d << 12) + n] = f2bf(o[d]);
}

// ============ K3: proj (MFMA) + residual + LN2 ============
__global__ __launch_bounds__(256) void k3_proj_ln(
    const ushort_t* __restrict__ abt, const float* __restrict__ Wproj, const float* __restrict__ bproj,
    const float* __restrict__ g2, const float* __restrict__ b2,
    float* __restrict__ xh, ushort_t* __restrict__ zt)
{
    __shared__ __align__(16) float    Cs[96 * 69];
    __shared__ __align__(16) ushort_t As[64 * 104];
    __shared__ __align__(16) ushort_t Bs[96 * 104];
    __shared__ float lnm[64], lnr[64];
    const int tid = threadIdx.x;
    const long bn0 = (long)blockIdx.x * 64;
    const int b = (int)(bn0 >> 12);
    const int hw0 = (int)(bn0 & 4095);

    // stage A from channel-major bf16 ab: coalesced u32 reads (2 pos), transpose writes
    for (int i = 0; i < 12; ++i) {
        int idx = i * 256 + tid;
        int c = idx / 32, ph = idx % 32;
        unsigned v = *(const unsigned*)&abt[(((long)(b*96 + c)) << 12) + hw0 + 2*ph];
        As[(2*ph  )*104 + c] = (ushort_t)(v & 0xFFFF);
        As[(2*ph+1)*104 + c] = (ushort_t)(v >> 16);
    }
    for (int i = 0; i < 18; ++i) {
        int idx = i * 256 + tid;
        int o = idx / 48, cp = idx % 48;
        const float* wp = Wproj + (long)o*96 + 2*cp;
        unsigned lo = f2bf(wp[0]), hi = f2bf(wp[1]);
        *(unsigned*)&Bs[o * 104 + 2*cp] = lo | (hi << 16);
    }
    __syncthreads();
    const int lane = tid & 63, wv = tid >> 6;
    const int ln = lane & 15, qd = lane >> 4;
    f32x4 acc[6];
    #pragma unroll
    for (int t = 0; t < 6; ++t) acc[t] = (f32x4){0.f, 0.f, 0.f, 0.f};
    #pragma unroll
    for (int kc = 0; kc < 3; ++kc) {
        short8 a = *(const short8*)&As[(wv*16 + ln)*104 + kc*32 + qd*8];
        #pragma unroll
        for (int t = 0; t < 6; ++t) {
            short8 bf = *(const short8*)&Bs[(t*16 + ln)*104 + kc*32 + qd*8];
            acc[t] = __builtin_amdgcn_mfma_f32_16x16x32_bf16(a, bf, acc[t], 0, 0, 0);
        }
    }
    #pragma unroll
    for (int t = 0; t < 6; ++t)
        #pragma unroll
        for (int r = 0; r < 4; ++r)
            Cs[(t*16 + ln)*69 + (wv*16 + qd*4 + r)] = acc[t][r];
    __syncthreads();
    // pass A: residual update xh' = xh + proj + bias (coalesced), keep in Cs
    for (int i = 0; i < 24; ++i) {
        int idx = i * 256 + tid;
        int p = idx / 96, c = idx % 96;
        long g = (bn0 + p) * 96 + c;
        float v = Cs[c*69 + p] + bproj[c] + xh[g];
        xh[g] = v;
        Cs[c*69 + p] = v;
    }
    __syncthreads();
    // LN2 stats
    {
        int p = tid >> 2, part = tid & 3, c0 = part * 24;
        float s = 0.f, ss = 0.f;
        for (int c = c0; c < c0 + 24; ++c) { float v = Cs[c*69 + p]; s += v; ss += v*v; }
        s  += __shfl_xor(s, 1);  s  += __shfl_xor(s, 2);
        ss += __shfl_xor(ss, 1); ss += __shfl_xor(ss, 2);
        float m = s * (1.f/96.f);
        float rstd = rsqrtf(ss * (1.f/96.f) - m*m + 1e-5f);
        if (part == 0) { lnm[p] = m; lnr[p] = rstd; }
    }
    __syncthreads();
    // pass B: z = LN2(xh') -> bf16 position-major, coalesced u32 stores
    for (int i = 0; i < 12; ++i) {
        int idx = i * 256 + tid;
        int p = idx / 48, cp = idx % 48;
        float m = lnm[p], rs = lnr[p];
        int c0 = 2*cp;
        float v0 = (Cs[(c0  )*69 + p] - m) * rs * g2[c0  ] + b2[c0  ];
        float v1 = (Cs[(c0+1)*69 + p] - m) * rs * g2[c0+1] + b2[c0+1];
        unsigned lo = f2bf(v0), hi = f2bf(v1);
        *(unsigned*)&zt[(bn0 + p) * 96 + c0] = lo | (hi << 16);
    }
}

// ============ K4: MLP fc1 (MFMA) + exact GELU ============
__global__ __launch_bounds__(256) void k4_mlp1(
    const ushort_t* __restrict__ zt, const float* __restrict__ W1, const float* __restrict__ bm1,
    ushort_t* __restrict__ hbt)
{
    __shared__ __align__(16) float    Cs[96 * 69];
    __shared__ __align__(16) ushort_t As[64 * 104];
    __shared__ __align__(16) ushort_t Bs[96 * 104];
    const int tid = threadIdx.x;
    const long bn0 = (long)blockIdx.x * 64;
    const int ch = blockIdx.y;

    for (int i = 0; i < 12; ++i) {      // A: already bf16 position-major, direct
        int idx = i * 256 + tid;
        int p = idx / 48, cp = idx % 48;
        *(unsigned*)&As[p * 104 + 2*cp] = *(const unsigned*)&zt[(bn0 + p) * 96 + 2*cp];
    }
    for (int i = 0; i < 18; ++i) {
        int idx = i * 256 + tid;
        int o = idx / 48, cp = idx % 48;
        const float* wp = W1 + (long)(ch*96 + o)*96 + 2*cp;
        unsigned lo = f2bf(wp[0]), hi = f2bf(wp[1]);
        *(unsigned*)&Bs[o * 104 + 2*cp] = lo | (hi << 16);
    }
    __syncthreads();
    const int lane = tid & 63, wv = tid >> 6;
    const int ln = lane & 15, qd = lane >> 4;
    f32x4 acc[6];
    #pragma unroll
    for (int t = 0; t < 6; ++t) acc[t] = (f32x4){0.f, 0.f, 0.f, 0.f};
    #pragma unroll
    for (int kc = 0; kc < 3; ++kc) {
        short8 a = *(const short8*)&As[(wv*16 + ln)*104 + kc*32 + qd*8];
        #pragma unroll
        for (int t = 0; t < 6; ++t) {
            short8 bf = *(const short8*)&Bs[(t*16 + ln)*104 + kc*32 + qd*8];
            acc[t] = __builtin_amdgcn_mfma_f32_16x16x32_bf16(a, bf, acc[t], 0, 0, 0);
        }
    }
    #pragma unroll
    for (int t = 0; t < 6; ++t)
        #pragma unroll
        for (int r = 0; r < 4; ++r)
            Cs[(t*16 + ln)*69 + (wv*16 + qd*4 + r)] = acc[t][r];
    __syncthreads();
    for (int i = 0; i < 12; ++i) {
        int idx = i * 256 + tid;
        int p = idx / 48, cp = idx % 48;
        int c0 = 2*cp;
        float v0 = Cs[(c0  )*69 + p] + bm1[ch*96 + c0  ];
        float v1 = Cs[(c0+1)*69 + p] + bm1[ch*96 + c0+1];
        v0 = 0.5f * v0 * (1.f + erff(v0 * 0.70710678118654752f));
        v1 = 0.5f * v1 * (1.f + erff(v1 * 0.70710678118654752f));
        unsigned lo = f2bf(v0), hi = f2bf(v1);
        *(unsigned*)&hbt[(bn0 + p) * 384 + ch*96 + c0] = lo | (hi << 16);
    }
}

// ============ K5: MLP fc2 (MFMA) + residual + ReLU + L2 normalize ============
__global__ __launch_bounds__(256) void k5_mlp2_norm(
    const ushort_t* __restrict__ hbt, const float* __restrict__ W2, const float* __restrict__ bm2,
    const float* __restrict__ xh, float* __restrict__ xcn)
{
    __shared__ __align__(16) float    Cs[96 * 69];
    __shared__ __align__(16) ushort_t As[64 * 104];
    __shared__ __align__(16) ushort_t Bs[96 * 104];
    __shared__ float lnr[64];
    const int tid = threadIdx.x;
    const long bn0 = (long)blockIdx.x * 64;
    const int lane = tid & 63, wv = tid >> 6;
    const int ln = lane & 15, qd = lane >> 4;
    f32x4 acc[6];
    #pragma unroll
    for (int t = 0; t < 6; ++t) acc[t] = (f32x4){0.f, 0.f, 0.f, 0.f};

    for (int kb = 0; kb < 4; ++kb) {
        __syncthreads();
        for (int i = 0; i < 12; ++i) {
            int idx = i * 256 + tid;
            int p = idx / 48, cp = idx % 48;
            *(unsigned*)&As[p * 104 + 2*cp] =
                *(const unsigned*)&hbt[(bn0 + p) * 384 + kb*96 + 2*cp];
        }
        for (int i = 0; i < 18; ++i) {
            int idx = i * 256 + tid;
            int o = idx / 48, cp = idx % 48;
            const float* wp = W2 + (long)o*384 + kb*96 + 2*cp;
            unsigned lo = f2bf(wp[0]), hi = f2bf(wp[1]);
            *(unsigned*)&Bs[o * 104 + 2*cp] = lo | (hi << 16);
        }
        __syncthreads();
        #pragma unroll
        for (int kc = 0; kc < 3; ++kc) {
            short8 a = *(const short8*)&As[(wv*16 + ln)*104 + kc*32 + qd*8];
            #pragma unroll
            for (int t = 0; t < 6; ++t) {
                short8 bf = *(const short8*)&Bs[(t*16 + ln)*104 + kc*32 + qd*8];
                acc[t] = __builtin_amdgcn_mfma_f32_16x16x32_bf16(a, bf, acc[t], 0, 0, 0);
            }
        }
    }
    #pragma unroll
    for (int t = 0; t < 6; ++t)
        #pragma unroll
        for (int r = 0; r < 4; ++r)
            Cs[(t*16 + ln)*69 + (wv*16 + qd*4 + r)] = acc[t][r];
    __syncthreads();
    // pass A: + bias + residual, relu
    for (int i = 0; i < 24; ++i) {
        int idx = i * 256 + tid;
        int p = idx / 96, c = idx % 96;
        float v = Cs[c*69 + p] + bm2[c] + xh[(bn0 + p) * 96 + c];
        Cs[c*69 + p] = fmaxf(v, 0.f);
    }
    __syncthreads();
    // L2 norm over channels
    {
        int p = tid >> 2, part = tid & 3, c0 = part * 24;
        float ss = 0.f;
        for (int c = c0; c < c0 + 24; ++c) { float v = Cs[c*69 + p]; ss += v*v; }
        ss += __shfl_xor(ss, 1); ss += __shfl_xor(ss, 2);
        if (part == 0) lnr[p] = 1.f / fmaxf(sqrtf(ss), 1e-12f);
    }
    __syncthreads();
    // pass B: xcn position-major fp32, float2 coalesced
    for (int i = 0; i < 12; ++i) {
        int idx = i * 256 + tid;
        int p = idx / 48, cp = idx % 48;
        float inv = lnr[p];
        float2 v = make_float2(Cs[(2*cp)*69 + p] * inv, Cs[(2*cp+1)*69 + p] * inv);
        *(float2*)&xcn[(bn0 + p) * 96 + 2*cp] = v;
    }
}

// ============ K6: 5x5 self-correlation (unchanged) ============
__global__ __launch_bounds__(256) void k6_selfcorr(
    const float* __restrict__ xcn, float* __restrict__ out)
{
    __shared__ float xt[5 * 20 * 97];
    const int tid = threadIdx.x;
    const int wc = blockIdx.x;
    const int h  = blockIdx.y;
    const int b  = blockIdx.z;
    const int w0 = wc * 16;

    for (int i = 0; i < 38; ++i) {
        int idx = i * 256 + tid;
        if (idx < 9600) {
            int r = idx / (20 * 96);
            int rem = idx - r * (20 * 96);
            int wi = rem / 96, c = rem - wi * 96;
            int hh = h + r - 2, ww = w0 + wi - 2;
            float v = 0.f;
            if ((unsigned)hh < 64u && (unsigned)ww < 64u)
                v = xcn[(((long)b << 12) + (hh << 6) + ww) * 96 + c];
            xt[(r * 20 + wi) * 97 + c] = v;
        }
    }
    __syncthreads();
    const long obase = ((long)b * 96 * 4096 + (long)h * 64) * 25;
    for (int i = 0; i < 150; ++i) {
        int o = i * 256 + tid;
        int c = o / 400;
        int r2 = o - c * 400;
        int lw = r2 / 25, k = r2 - lw * 25;
        int ki = k / 5, kj = k - ki * 5;
        float center = xt[(2 * 20 + lw + 2) * 97 + c];
        float neigh  = xt[(ki * 20 + lw + kj) * 97 + c];
        out[obase + (long)c * (4096 * 25) + (w0 + lw) * 25 + k] = center * neigh;
    }
}

// ============ launcher ============
extern "C" void kernel_launch(void* const* d_in, const int* in_sizes, int n_in,
                              void* d_out, int out_size, void* d_ws, size_t ws_size,
                              hipStream_t stream)
{
    const float* x     = (const float*)d_in[0];
    const float* g1    = (const float*)d_in[1];
    const float* b1    = (const float*)d_in[2];
    const float* Wqkv  = (const float*)d_in[3];
    const float* bqkv  = (const float*)d_in[4];
    const float* Wproj = (const float*)d_in[5];
    const float* bproj = (const float*)d_in[6];
    const float* g2    = (const float*)d_in[7];
    const float* b2    = (const float*)d_in[8];
    const float* W1    = (const float*)d_in[9];
    const float* bm1   = (const float*)d_in[10];
    const float* W2    = (const float*)d_in[11];
    const float* bm2   = (const float*)d_in[12];
    float* out = (float*)d_out;

    char* w = (char*)d_ws;
    float*    xh   = (float*)w;    w += (size_t)BN * 96  * 4;
    float*    xcn  = (float*)w;    w += (size_t)BN * 96  * 4;
    ushort_t* qkvt = (ushort_t*)w; w += (size_t)BN * 288 * 2;
    ushort_t* abt  = (ushort_t*)w; w += (size_t)BN * 96  * 2;
    ushort_t* zt   = (ushort_t*)w; w += (size_t)BN * 96  * 2;
    ushort_t* hbt  = (ushort_t*)w;

    k1_ln_qkv   <<<BN / 64, 256, 0, stream>>>(x, g1, b1, Wqkv, bqkv, xh, qkvt);
    k2_attn     <<<(BN * 6) / 256, 256, 0, stream>>>(qkvt, abt);
    k3_proj_ln  <<<BN / 64, 256, 0, stream>>>(abt, Wproj, bproj, g2, b2, xh, zt);
    k4_mlp1     <<<dim3(BN / 64, 4), 256, 0, stream>>>(zt, W1, bm1, hbt);
    k5_mlp2_norm<<<BN / 64, 256, 0, stream>>>(hbt, W2, bm2, xh, xcn);
    k6_selfcorr <<<dim3(4, 64, 8), 256, 0, stream>>>(xcn, out);
}

// Round 3
// 479.731 us; speedup vs baseline: 1.3130x; 1.0273x over previous
//
#include <hip/hip_runtime.h>
#include <math.h>

#define NN 4096            // H*W
#define BN 32768           // B*H*W

using short8 = __attribute__((ext_vector_type(8))) short;
using f32x4  = __attribute__((ext_vector_type(4))) float;
typedef unsigned short ushort_t;

__device__ inline ushort_t f2bf(float f) {
    unsigned u = __builtin_bit_cast(unsigned, f);
    u += 0x7FFFu + ((u >> 16) & 1u);        // RNE
    return (ushort_t)(u >> 16);
}
__device__ inline float bflo(unsigned u) {  // low 16 bits -> float
    return __builtin_bit_cast(float, u << 16);
}
__device__ inline float bfhi(unsigned u) {  // high 16 bits -> float
    return __builtin_bit_cast(float, u & 0xFFFF0000u);
}
__device__ inline float bf2f(ushort_t h) {
    return __builtin_bit_cast(float, ((unsigned)h) << 16);
}

// ============ K0: one-shot weight fp32 -> bf16 conversion ============
// layout in wb: [Wqkv 27648][Wproj 9216][W1 36864][W2 36864]
__global__ __launch_bounds__(256) void k0_cvt(
    const float* __restrict__ Wqkv, const float* __restrict__ Wproj,
    const float* __restrict__ W1, const float* __restrict__ W2,
    ushort_t* __restrict__ wb)
{
    int i = blockIdx.x * 256 + threadIdx.x;   // 110592 total
    float v;
    if (i < 27648)      v = Wqkv[i];
    else if (i < 36864) v = Wproj[i - 27648];
    else if (i < 73728) v = W1[i - 36864];
    else                v = W2[i - 73728];
    wb[i] = f2bf(v);
}

// ============ K1: LN1 + QKV (MFMA) -> qkvt paired-channel bf16 ============
// qkvt u32 plane layout: plane = b*144 + ch*48 + cp  (cp = channel pair), 4096 u32 per plane
__global__ __launch_bounds__(256) void k1_ln_qkv(
    const float* __restrict__ x, const float* __restrict__ g1, const float* __restrict__ b1,
    const ushort_t* __restrict__ wqkv_b, const float* __restrict__ bqkv,
    unsigned* __restrict__ qkvt32)
{
    __shared__ __align__(16) float    Cs[96 * 69];
    __shared__ __align__(16) ushort_t As[64 * 104];
    __shared__ __align__(16) ushort_t Bs[96 * 104];
    const int tid = threadIdx.x;
    const long bn0 = (long)blockIdx.x * 64;
    const int b = (int)(bn0 >> 12);
    const int n0 = (int)(bn0 & 4095);
    const unsigned* wqkv32 = (const unsigned*)wqkv_b;

    // stage x tile [c][p], coalesced
    for (int i = 0; i < 24; ++i) {
        int idx = i * 256 + tid;
        int c = idx >> 6, p = idx & 63;
        Cs[c * 69 + p] = x[((long)(b * 96 + c) << 12) + n0 + p];
    }
    __syncthreads();
    // LayerNorm in place: 4 threads per position
    {
        int p = tid >> 2, part = tid & 3, c0 = part * 24;
        float s = 0.f, ss = 0.f;
        for (int c = c0; c < c0 + 24; ++c) { float v = Cs[c*69 + p]; s += v; ss += v*v; }
        s  += __shfl_xor(s, 1);  s  += __shfl_xor(s, 2);
        ss += __shfl_xor(ss, 1); ss += __shfl_xor(ss, 2);
        float m = s * (1.f/96.f);
        float rstd = rsqrtf(ss * (1.f/96.f) - m*m + 1e-5f);
        for (int c = c0; c < c0 + 24; ++c)
            Cs[c*69 + p] = (Cs[c*69 + p] - m) * rstd * g1[c] + b1[c];
    }
    __syncthreads();
    // transpose-convert -> As bf16 [p][c]
    for (int i = 0; i < 12; ++i) {
        int idx = i * 256 + tid;
        int p = idx / 48, cp = idx % 48;
        unsigned lo = f2bf(Cs[(2*cp  )*69 + p]);
        unsigned hi = f2bf(Cs[(2*cp+1)*69 + p]);
        *(unsigned*)&As[p * 104 + 2*cp] = lo | (hi << 16);
    }

    const int lane = tid & 63, wv = tid >> 6;
    const int ln = lane & 15, qd = lane >> 4;
    for (int ch = 0; ch < 3; ++ch) {
        __syncthreads();
        for (int i = 0; i < 18; ++i) {        // stage pre-converted bf16 weights
            int idx = i * 256 + tid;
            int o = idx / 48, cp = idx % 48;
            *(unsigned*)&Bs[o * 104 + 2*cp] = wqkv32[(ch*96 + o)*48 + cp];
        }
        __syncthreads();
        f32x4 acc[6];
        #pragma unroll
        for (int t = 0; t < 6; ++t) acc[t] = (f32x4){0.f, 0.f, 0.f, 0.f};
        #pragma unroll
        for (int kc = 0; kc < 3; ++kc) {
            short8 a = *(const short8*)&As[(wv*16 + ln)*104 + kc*32 + qd*8];
            #pragma unroll
            for (int t = 0; t < 6; ++t) {
                short8 bf = *(const short8*)&Bs[(t*16 + ln)*104 + kc*32 + qd*8];
                acc[t] = __builtin_amdgcn_mfma_f32_16x16x32_bf16(a, bf, acc[t], 0, 0, 0);
            }
        }
        #pragma unroll
        for (int t = 0; t < 6; ++t)
            #pragma unroll
            for (int r = 0; r < 4; ++r)
                Cs[(t*16 + ln)*69 + (wv*16 + qd*4 + r)] = acc[t][r];
        __syncthreads();
        // epilogue: +bias, pack channel pairs, coalesced dword stores
        for (int i = 0; i < 12; ++i) {
            int idx = i * 256 + tid;
            int cp = idx / 64, p = idx % 64;
            int c = 2*cp;
            float b0v = bqkv[ch*96 + c], b1v = bqkv[ch*96 + c + 1];
            unsigned lo = f2bf(Cs[c*69 + p] + b0v);
            unsigned hi = f2bf(Cs[(c+1)*69 + p] + b1v);
            qkvt32[((long)(b*144 + ch*48 + cp) << 12) + n0 + p] = lo | (hi << 16);
        }
    }
}

// ============ K2: multi-dilate local attention (paired-channel dword loads) ============
__global__ __launch_bounds__(256) void k2_attn(
    const unsigned* __restrict__ qkvt32, unsigned* __restrict__ abt32)
{
    int t = blockIdx.x * 256 + threadIdx.x;   // BN*6
    int n = t & 4095;
    int r = t >> 12;                          // 48 combos
    int head = r & 1;
    int di = (r >> 1) % 3;
    int b = r / 6;
    int h = n >> 6, w = n & 63;
    int dil = di + 1;
    const int cp0 = di*16 + head*8;           // channel-pair offset (8 pairs = 16 ch)
    const unsigned* Q = qkvt32 + ((long)(b*144 +      cp0) << 12);
    const unsigned* K = qkvt32 + ((long)(b*144 + 48 + cp0) << 12);
    const unsigned* V = qkvt32 + ((long)(b*144 + 96 + cp0) << 12);

    float q[16];
    #pragma unroll
    for (int j = 0; j < 8; ++j) {
        unsigned u = Q[((long)j << 12) + n];
        q[2*j] = bflo(u); q[2*j+1] = bfhi(u);
    }

    float logits[9];
    #pragma unroll
    for (int ki = 0; ki < 3; ++ki)
        #pragma unroll
        for (int kj = 0; kj < 3; ++kj) {
            int hh = h + (ki-1)*dil, ww = w + (kj-1)*dil;
            float l = 0.f;
            if ((unsigned)hh < 64u && (unsigned)ww < 64u) {
                int nn = (hh << 6) + ww;
                #pragma unroll
                for (int j = 0; j < 8; ++j) {
                    unsigned u = K[((long)j << 12) + nn];
                    l += q[2*j] * bflo(u) + q[2*j+1] * bfhi(u);
                }
            }
            logits[ki*3 + kj] = l * 0.25f;
        }
    float m = logits[0];
    #pragma unroll
    for (int k = 1; k < 9; ++k) m = fmaxf(m, logits[k]);
    float e[9], s = 0.f;
    #pragma unroll
    for (int k = 0; k < 9; ++k) { e[k] = expf(logits[k] - m); s += e[k]; }
    float inv = 1.f / s;

    float o[16];
    #pragma unroll
    for (int d = 0; d < 16; ++d) o[d] = 0.f;
    #pragma unroll
    for (int ki = 0; ki < 3; ++ki)
        #pragma unroll
        for (int kj = 0; kj < 3; ++kj) {
            int hh = h + (ki-1)*dil, ww = w + (kj-1)*dil;
            if ((unsigned)hh < 64u && (unsigned)ww < 64u) {
                int nn = (hh << 6) + ww;
                float wgt = e[ki*3 + kj] * inv;
                #pragma unroll
                for (int j = 0; j < 8; ++j) {
                    unsigned u = V[((long)j << 12) + nn];
                    o[2*j]   += wgt * bflo(u);
                    o[2*j+1] += wgt * bfhi(u);
                }
            }
        }
    #pragma unroll
    for (int j = 0; j < 8; ++j) {
        unsigned lo = f2bf(o[2*j]), hi = f2bf(o[2*j+1]);
        abt32[((long)(b*48 + cp0 + j) << 12) + n] = lo | (hi << 16);
    }
}

// ============ K345: proj + residual + LN2 + MLP + residual + ReLU + L2norm ============
__global__ __launch_bounds__(256) void k345(
    const unsigned* __restrict__ abt32, const float* __restrict__ x,
    const ushort_t* __restrict__ wproj_b, const float* __restrict__ bproj,
    const float* __restrict__ g2, const float* __restrict__ b2,
    const ushort_t* __restrict__ w1_b, const float* __restrict__ bm1,
    const ushort_t* __restrict__ w2_b, const float* __restrict__ bm2,
    float* __restrict__ xcn)
{
    __shared__ __align__(16) float    Cs[96 * 69];     // 26.5 KB
    __shared__ __align__(16) ushort_t As[64 * 104];    // 13.3 KB (z frags)
    __shared__ __align__(16) ushort_t Ah[64 * 104];    // 13.3 KB (h frags)
    __shared__ __align__(16) ushort_t Bs[96 * 104];    // 20  KB (weights)
    __shared__ float lnm[64], lnr[64];
    const int tid = threadIdx.x;
    const long bn0 = (long)blockIdx.x * 64;
    const int b = (int)(bn0 >> 12);
    const int n0 = (int)(bn0 & 4095);
    const unsigned* wproj32 = (const unsigned*)wproj_b;
    const unsigned* w1_32   = (const unsigned*)w1_b;
    const unsigned* w2_32   = (const unsigned*)w2_b;
    const int lane = tid & 63, wv = tid >> 6;
    const int ln = lane & 15, qd = lane >> 4;

    // stage attention-out A-frags (paired dwords, coalesced)
    for (int i = 0; i < 12; ++i) {
        int idx = i * 256 + tid;
        int cp = idx / 64, p = idx % 64;
        *(unsigned*)&As[p * 104 + 2*cp] = abt32[((long)(b*48 + cp) << 12) + n0 + p];
    }
    // stage Wproj bf16
    for (int i = 0; i < 18; ++i) {
        int idx = i * 256 + tid;
        int o = idx / 48, cp = idx % 48;
        *(unsigned*)&Bs[o * 104 + 2*cp] = wproj32[o*48 + cp];
    }
    __syncthreads();
    // proj MFMA
    {
        f32x4 acc[6];
        #pragma unroll
        for (int t = 0; t < 6; ++t) acc[t] = (f32x4){0.f, 0.f, 0.f, 0.f};
        #pragma unroll
        for (int kc = 0; kc < 3; ++kc) {
            short8 a = *(const short8*)&As[(wv*16 + ln)*104 + kc*32 + qd*8];
            #pragma unroll
            for (int t = 0; t < 6; ++t) {
                short8 bf = *(const short8*)&Bs[(t*16 + ln)*104 + kc*32 + qd*8];
                acc[t] = __builtin_amdgcn_mfma_f32_16x16x32_bf16(a, bf, acc[t], 0, 0, 0);
            }
        }
        #pragma unroll
        for (int t = 0; t < 6; ++t)
            #pragma unroll
            for (int r = 0; r < 4; ++r)
                Cs[(t*16 + ln)*69 + (wv*16 + qd*4 + r)] = acc[t][r];
    }
    __syncthreads();
    // residual xh' = x + proj + bias; keep xh' in registers (resid) and in Cs
    float resid[24];
    #pragma unroll
    for (int i = 0; i < 24; ++i) {
        int idx = i * 256 + tid;
        int c = idx >> 6, p = idx & 63;
        float v = Cs[c*69 + p] + bproj[c] + x[((long)(b*96 + c) << 12) + n0 + p];
        resid[i] = v;
        Cs[c*69 + p] = v;
    }
    __syncthreads();
    // LN2 stats
    {
        int p = tid >> 2, part = tid & 3, c0 = part * 24;
        float s = 0.f, ss = 0.f;
        for (int c = c0; c < c0 + 24; ++c) { float v = Cs[c*69 + p]; s += v; ss += v*v; }
        s  += __shfl_xor(s, 1);  s  += __shfl_xor(s, 2);
        ss += __shfl_xor(ss, 1); ss += __shfl_xor(ss, 2);
        float m = s * (1.f/96.f);
        float rstd = rsqrtf(ss * (1.f/96.f) - m*m + 1e-5f);
        if (part == 0) { lnm[p] = m; lnr[p] = rstd; }
    }
    __syncthreads();
    // z = LN2(xh') -> As bf16 frags (overwrite attention frags)
    for (int i = 0; i < 12; ++i) {
        int idx = i * 256 + tid;
        int p = idx / 48, cp = idx % 48;
        float m = lnm[p], rs = lnr[p];
        int c = 2*cp;
        unsigned lo = f2bf((Cs[(c  )*69 + p] - m) * rs * g2[c  ] + b2[c  ]);
        unsigned hi = f2bf((Cs[(c+1)*69 + p] - m) * rs * g2[c+1] + b2[c+1]);
        *(unsigned*)&As[p * 104 + 2*cp] = lo | (hi << 16);
    }

    // MLP: h = gelu(z @ W1^T + bm1); y = h @ W2^T, accumulated over 4 K-chunks
    f32x4 acc2[6];
    #pragma unroll
    for (int t = 0; t < 6; ++t) acc2[t] = (f32x4){0.f, 0.f, 0.f, 0.f};
    for (int kb = 0; kb < 4; ++kb) {
        __syncthreads();    // Bs/Ah safe to overwrite; also covers As-frag write on kb=0
        for (int i = 0; i < 18; ++i) {
            int idx = i * 256 + tid;
            int o = idx / 48, cp = idx % 48;
            *(unsigned*)&Bs[o * 104 + 2*cp] = w1_32[(kb*96 + o)*48 + cp];
        }
        __syncthreads();
        f32x4 acch[6];
        #pragma unroll
        for (int t = 0; t < 6; ++t) acch[t] = (f32x4){0.f, 0.f, 0.f, 0.f};
        #pragma unroll
        for (int kc = 0; kc < 3; ++kc) {
            short8 a = *(const short8*)&As[(wv*16 + ln)*104 + kc*32 + qd*8];
            #pragma unroll
            for (int t = 0; t < 6; ++t) {
                short8 bf = *(const short8*)&Bs[(t*16 + ln)*104 + kc*32 + qd*8];
                acch[t] = __builtin_amdgcn_mfma_f32_16x16x32_bf16(a, bf, acch[t], 0, 0, 0);
            }
        }
        // gelu -> Ah A-frag layout [p][hc]
        #pragma unroll
        for (int t = 0; t < 6; ++t) {
            float bias = bm1[kb*96 + t*16 + ln];
            #pragma unroll
            for (int r = 0; r < 4; ++r) {
                float v = acch[t][r] + bias;
                v = 0.5f * v * (1.f + erff(v * 0.70710678118654752f));
                Ah[(wv*16 + qd*4 + r)*104 + t*16 + ln] = f2bf(v);
            }
        }
        __syncthreads();    // Ah written, Bs readers done -> restage Bs with W2
        for (int i = 0; i < 18; ++i) {
            int idx = i * 256 + tid;
            int o = idx / 48, cp = idx % 48;
            *(unsigned*)&Bs[o * 104 + 2*cp] = w2_32[o*192 + kb*48 + cp];
        }
        __syncthreads();
        #pragma unroll
        for (int kc = 0; kc < 3; ++kc) {
            short8 a = *(const short8*)&Ah[(wv*16 + ln)*104 + kc*32 + qd*8];
            #pragma unroll
            for (int t = 0; t < 6; ++t) {
                short8 bf = *(const short8*)&Bs[(t*16 + ln)*104 + kc*32 + qd*8];
                acc2[t] = __builtin_amdgcn_mfma_f32_16x16x32_bf16(a, bf, acc2[t], 0, 0, 0);
            }
        }
    }
    __syncthreads();
    #pragma unroll
    for (int t = 0; t < 6; ++t)
        #pragma unroll
        for (int r = 0; r < 4; ++r)
            Cs[(t*16 + ln)*69 + (wv*16 + qd*4 + r)] = acc2[t][r];
    __syncthreads();
    // final residual + relu
    #pragma unroll
    for (int i = 0; i < 24; ++i) {
        int idx = i * 256 + tid;
        int c = idx >> 6, p = idx & 63;
        float v = Cs[c*69 + p] + bm2[c] + resid[i];
        Cs[c*69 + p] = fmaxf(v, 0.f);
    }
    __syncthreads();
    // L2 norm over channels
    {
        int p = tid >> 2, part = tid & 3, c0 = part * 24;
        float ss = 0.f;
        for (int c = c0; c < c0 + 24; ++c) { float v = Cs[c*69 + p]; ss += v*v; }
        ss += __shfl_xor(ss, 1); ss += __shfl_xor(ss, 2);
        if (part == 0) lnr[p] = 1.f / fmaxf(sqrtf(ss), 1e-12f);
    }
    __syncthreads();
    // write xcn position-major fp32
    for (int i = 0; i < 12; ++i) {
        int idx = i * 256 + tid;
        int p = idx / 48, cp = idx % 48;
        float inv = lnr[p];
        float2 v = make_float2(Cs[(2*cp)*69 + p] * inv, Cs[(2*cp+1)*69 + p] * inv);
        *(float2*)&xcn[(bn0 + p) * 96 + 2*cp] = v;
    }
}

// ============ K6: 5x5 self-correlation (float4 stores) ============
__global__ __launch_bounds__(256) void k6_selfcorr(
    const float* __restrict__ xcn, float* __restrict__ out)
{
    __shared__ float xt[5 * 20 * 97];
    const int tid = threadIdx.x;
    const int wc = blockIdx.x;
    const int h  = blockIdx.y;
    const int b  = blockIdx.z;
    const int w0 = wc * 16;

    for (int i = 0; i < 38; ++i) {
        int idx = i * 256 + tid;
        if (idx < 9600) {
            int r = idx / (20 * 96);
            int rem = idx - r * (20 * 96);
            int wi = rem / 96, c = rem - wi * 96;
            int hh = h + r - 2, ww = w0 + wi - 2;
            float v = 0.f;
            if ((unsigned)hh < 64u && (unsigned)ww < 64u)
                v = xcn[(((long)b << 12) + (hh << 6) + ww) * 96 + c];
            xt[(r * 20 + wi) * 97 + c] = v;
        }
    }
    __syncthreads();
    // out float4 base for this (b,h,wc)
    float4* out4 = (float4*)out;
    const long ob4 = (long)b * 2457600 + (long)h * 400 + wc * 100;
    for (int i = 0; i < 38; ++i) {
        int idx = i * 256 + tid;             // 9600 float4 slots
        if (idx < 9600) {
            int c = idx / 100;
            int r4 = idx - c * 100;
            float4 v;
            #pragma unroll
            for (int j = 0; j < 4; ++j) {
                int r = r4 * 4 + j;
                int lw = r / 25, k = r - lw * 25;
                int ki = k / 5, kj = k - ki * 5;
                float center = xt[(42 + lw) * 97 + c];
                float neigh  = xt[(ki * 20 + lw + kj) * 97 + c];
                (&v.x)[j] = center * neigh;
            }
            out4[ob4 + (long)c * 25600 + r4] = v;
        }
    }
}

// ============ launcher ============
extern "C" void kernel_launch(void* const* d_in, const int* in_sizes, int n_in,
                              void* d_out, int out_size, void* d_ws, size_t ws_size,
                              hipStream_t stream)
{
    const float* x     = (const float*)d_in[0];
    const float* g1    = (const float*)d_in[1];
    const float* b1    = (const float*)d_in[2];
    const float* Wqkv  = (const float*)d_in[3];
    const float* bqkv  = (const float*)d_in[4];
    const float* Wproj = (const float*)d_in[5];
    const float* bproj = (const float*)d_in[6];
    const float* g2    = (const float*)d_in[7];
    const float* b2    = (const float*)d_in[8];
    const float* W1    = (const float*)d_in[9];
    const float* bm1   = (const float*)d_in[10];
    const float* W2    = (const float*)d_in[11];
    const float* bm2   = (const float*)d_in[12];
    float* out = (float*)d_out;

    char* w = (char*)d_ws;
    unsigned* qkvt32 = (unsigned*)w;  w += (size_t)BN * 288 * 2;   // bf16 pairs
    unsigned* abt32  = (unsigned*)w;  w += (size_t)BN * 96 * 2;
    float*    xcn    = (float*)w;     w += (size_t)BN * 96 * 4;
    ushort_t* wb     = (ushort_t*)w;  w += (size_t)110592 * 2;
    ushort_t* wqkv_b = wb;
    ushort_t* wproj_b= wb + 27648;
    ushort_t* w1_b   = wb + 36864;
    ushort_t* w2_b   = wb + 73728;

    k0_cvt     <<<432, 256, 0, stream>>>(Wqkv, Wproj, W1, W2, wb);
    k1_ln_qkv  <<<BN / 64, 256, 0, stream>>>(x, g1, b1, wqkv_b, bqkv, qkvt32);
    k2_attn    <<<(BN * 6) / 256, 256, 0, stream>>>(qkvt32, abt32);
    k345       <<<BN / 64, 256, 0, stream>>>(abt32, x, wproj_b, bproj, g2, b2,
                                             w1_b, bm1, w2_b, bm2, xcn);
    k6_selfcorr<<<dim3(4, 64, 8), 256, 0, stream>>>(xcn, out);
}

// Round 5
// 436.003 us; speedup vs baseline: 1.4446x; 1.1003x over previous
//
#include <hip/hip_runtime.h>
#include <math.h>

#define NN 4096            // H*W
#define BN 32768           // B*H*W

using short8 = __attribute__((ext_vector_type(8))) short;
using f32x4  = __attribute__((ext_vector_type(4))) float;
typedef unsigned short ushort_t;

__device__ inline unsigned f2bfu(float f) {
    unsigned u = __builtin_bit_cast(unsigned, f);
    u += 0x7FFFu + ((u >> 16) & 1u);        // RNE
    return u >> 16;
}
__device__ inline ushort_t f2bf(float f) { return (ushort_t)f2bfu(f); }
__device__ inline unsigned pack2(float a, float b) { return f2bfu(a) | (f2bfu(b) << 16); }
__device__ inline float bflo(unsigned u) { return __builtin_bit_cast(float, u << 16); }
__device__ inline float bfhi(unsigned u) { return __builtin_bit_cast(float, u & 0xFFFF0000u); }

// ============ K1: LN1 + QKV (MFMA) -> qkvt paired-channel bf16 ============
// qkvt u32 plane layout: plane = b*144 + ch*48 + cp (cp = channel pair), 4096 u32/plane
__global__ __launch_bounds__(256) void k1_ln_qkv(
    const float* __restrict__ x, const float* __restrict__ g1, const float* __restrict__ b1,
    const float* __restrict__ Wqkv, const float* __restrict__ bqkv,
    unsigned* __restrict__ qkvt32)
{
    __shared__ __align__(16) float    Cs[96 * 69];
    __shared__ __align__(16) ushort_t As[64 * 104];
    __shared__ __align__(16) ushort_t Bs[96 * 104];
    const int tid = threadIdx.x;
    const long bn0 = (long)blockIdx.x * 64;
    const int b = (int)(bn0 >> 12);
    const int n0 = (int)(bn0 & 4095);

    // stage x tile [c][p], coalesced
    for (int i = 0; i < 24; ++i) {
        int idx = i * 256 + tid;
        int c = idx >> 6, p = idx & 63;
        Cs[c * 69 + p] = x[((long)(b * 96 + c) << 12) + n0 + p];
    }
    __syncthreads();
    // LayerNorm in place: 4 threads per position
    {
        int p = tid >> 2, part = tid & 3, c0 = part * 24;
        float s = 0.f, ss = 0.f;
        for (int c = c0; c < c0 + 24; ++c) { float v = Cs[c*69 + p]; s += v; ss += v*v; }
        s  += __shfl_xor(s, 1);  s  += __shfl_xor(s, 2);
        ss += __shfl_xor(ss, 1); ss += __shfl_xor(ss, 2);
        float m = s * (1.f/96.f);
        float rstd = rsqrtf(ss * (1.f/96.f) - m*m + 1e-5f);
        for (int c = c0; c < c0 + 24; ++c)
            Cs[c*69 + p] = (Cs[c*69 + p] - m) * rstd * g1[c] + b1[c];
    }
    __syncthreads();
    // transpose-convert -> As bf16 [p][c]
    for (int i = 0; i < 12; ++i) {
        int idx = i * 256 + tid;
        int p = idx / 48, cp = idx % 48;
        *(unsigned*)&As[p * 104 + 2*cp] = pack2(Cs[(2*cp)*69 + p], Cs[(2*cp+1)*69 + p]);
    }

    const int lane = tid & 63, wv = tid >> 6;
    const int ln = lane & 15, qd = lane >> 4;
    for (int ch = 0; ch < 3; ++ch) {
        __syncthreads();
        // stage weight chunk, inline fp32->bf16 (float4 reads, L2-resident)
        for (int i = 0; i < 9; ++i) {
            int idx = i * 256 + tid;
            int o = idx / 24, q4 = idx % 24;
            float4 wvv = *(const float4*)&Wqkv[(long)(ch*96 + o)*96 + q4*4];
            uint2 d; d.x = pack2(wvv.x, wvv.y); d.y = pack2(wvv.z, wvv.w);
            *(uint2*)&Bs[o * 104 + q4*4] = d;
        }
        __syncthreads();
        f32x4 acc[6];
        #pragma unroll
        for (int t = 0; t < 6; ++t) acc[t] = (f32x4){0.f, 0.f, 0.f, 0.f};
        #pragma unroll
        for (int kc = 0; kc < 3; ++kc) {
            short8 a = *(const short8*)&As[(wv*16 + ln)*104 + kc*32 + qd*8];
            #pragma unroll
            for (int t = 0; t < 6; ++t) {
                short8 bf = *(const short8*)&Bs[(t*16 + ln)*104 + kc*32 + qd*8];
                acc[t] = __builtin_amdgcn_mfma_f32_16x16x32_bf16(a, bf, acc[t], 0, 0, 0);
            }
        }
        #pragma unroll
        for (int t = 0; t < 6; ++t)
            #pragma unroll
            for (int r = 0; r < 4; ++r)
                Cs[(t*16 + ln)*69 + (wv*16 + qd*4 + r)] = acc[t][r];
        __syncthreads();
        // epilogue: +bias, pack channel pairs, coalesced dword stores
        for (int i = 0; i < 12; ++i) {
            int idx = i * 256 + tid;
            int cp = idx / 64, p = idx % 64;
            int c = 2*cp;
            unsigned d = pack2(Cs[c*69 + p] + bqkv[ch*96 + c],
                               Cs[(c+1)*69 + p] + bqkv[ch*96 + c + 1]);
            qkvt32[((long)(b*144 + ch*48 + cp) << 12) + n0 + p] = d;
        }
    }
}

// ============ K2345: attention + proj + resid + LN2 + MLP + resid + ReLU + L2norm ============
__global__ __launch_bounds__(256) void k2345(
    const unsigned* __restrict__ qkvt32, const float* __restrict__ x,
    const float* __restrict__ Wproj, const float* __restrict__ bproj,
    const float* __restrict__ g2, const float* __restrict__ b2,
    const float* __restrict__ W1, const float* __restrict__ bm1,
    const float* __restrict__ W2, const float* __restrict__ bm2,
    float* __restrict__ xcn)
{
    __shared__ __align__(16) float    Cs[96 * 69];     // 26.5 KB
    __shared__ __align__(16) ushort_t As[64 * 104];    // 13.3 KB (attn-out / z frags)
    __shared__ __align__(16) ushort_t Ah[64 * 104];    // 13.3 KB (h frags)
    __shared__ __align__(16) ushort_t Bs[96 * 104];    // 20  KB (weights)
    __shared__ float lnm[64], lnr[64];
    const int tid = threadIdx.x;
    const long bn0 = (long)blockIdx.x * 64;
    const int b = (int)(bn0 >> 12);
    const int n0 = (int)(bn0 & 4095);
    const int h0 = n0 >> 6;                 // this block's image row
    const int lane = tid & 63, wv = tid >> 6;
    const int ln = lane & 15, qd = lane >> 4;

    // ---- Phase A: dilate-attention for this row, output -> As bf16 [p][c] ----
    for (int it = 0; it < 2; ++it) {
        int item = it * 256 + tid;          // 64 pos x 6 (dil,head) = 384 items
        if (item < 384) {
            int p = item & 63;
            int r = item >> 6;
            int head = r & 1, di = r >> 1;
            int dil = di + 1;
            int cp0 = di*16 + head*8;       // dword-channel offset
            const unsigned* Q = qkvt32 + ((long)(b*144 +      cp0) << 12);
            const unsigned* K = qkvt32 + ((long)(b*144 + 48 + cp0) << 12);
            const unsigned* V = qkvt32 + ((long)(b*144 + 96 + cp0) << 12);
            int n = n0 + p, w = p;

            float q[16];
            #pragma unroll
            for (int j = 0; j < 8; ++j) {
                unsigned u = Q[((long)j << 12) + n];
                q[2*j] = bflo(u); q[2*j+1] = bfhi(u);
            }
            float logits[9];
            #pragma unroll
            for (int ki = 0; ki < 3; ++ki)
                #pragma unroll
                for (int kj = 0; kj < 3; ++kj) {
                    int hh = h0 + (ki-1)*dil, ww = w + (kj-1)*dil;
                    float l = 0.f;
                    if ((unsigned)hh < 64u && (unsigned)ww < 64u) {
                        int nn = (hh << 6) + ww;
                        #pragma unroll
                        for (int j = 0; j < 8; ++j) {
                            unsigned u = K[((long)j << 12) + nn];
                            l += q[2*j] * bflo(u) + q[2*j+1] * bfhi(u);
                        }
                    }
                    logits[ki*3 + kj] = l * 0.25f;
                }
            float m = logits[0];
            #pragma unroll
            for (int k = 1; k < 9; ++k) m = fmaxf(m, logits[k]);
            float e[9], s = 0.f;
            #pragma unroll
            for (int k = 0; k < 9; ++k) { e[k] = expf(logits[k] - m); s += e[k]; }
            float inv = 1.f / s;
            float o[16];
            #pragma unroll
            for (int d = 0; d < 16; ++d) o[d] = 0.f;
            #pragma unroll
            for (int ki = 0; ki < 3; ++ki)
                #pragma unroll
                for (int kj = 0; kj < 3; ++kj) {
                    int hh = h0 + (ki-1)*dil, ww = w + (kj-1)*dil;
                    if ((unsigned)hh < 64u && (unsigned)ww < 64u) {
                        int nn = (hh << 6) + ww;
                        float wgt = e[ki*3 + kj] * inv;
                        #pragma unroll
                        for (int j = 0; j < 8; ++j) {
                            unsigned u = V[((long)j << 12) + nn];
                            o[2*j]   += wgt * bflo(u);
                            o[2*j+1] += wgt * bfhi(u);
                        }
                    }
                }
            #pragma unroll
            for (int j = 0; j < 8; ++j)
                *(unsigned*)&As[p * 104 + 2*(cp0 + j)] = pack2(o[2*j], o[2*j+1]);
        }
    }
    // ---- stage Wproj bf16 (inline cvt) ----
    for (int i = 0; i < 9; ++i) {
        int idx = i * 256 + tid;
        int o = idx / 24, q4 = idx % 24;
        float4 wvv = *(const float4*)&Wproj[(long)o*96 + q4*4];
        uint2 d; d.x = pack2(wvv.x, wvv.y); d.y = pack2(wvv.z, wvv.w);
        *(uint2*)&Bs[o * 104 + q4*4] = d;
    }
    __syncthreads();
    // ---- proj MFMA ----
    {
        f32x4 acc[6];
        #pragma unroll
        for (int t = 0; t < 6; ++t) acc[t] = (f32x4){0.f, 0.f, 0.f, 0.f};
        #pragma unroll
        for (int kc = 0; kc < 3; ++kc) {
            short8 a = *(const short8*)&As[(wv*16 + ln)*104 + kc*32 + qd*8];
            #pragma unroll
            for (int t = 0; t < 6; ++t) {
                short8 bf = *(const short8*)&Bs[(t*16 + ln)*104 + kc*32 + qd*8];
                acc[t] = __builtin_amdgcn_mfma_f32_16x16x32_bf16(a, bf, acc[t], 0, 0, 0);
            }
        }
        #pragma unroll
        for (int t = 0; t < 6; ++t)
            #pragma unroll
            for (int r = 0; r < 4; ++r)
                Cs[(t*16 + ln)*69 + (wv*16 + qd*4 + r)] = acc[t][r];
    }
    __syncthreads();
    // ---- residual xh' = x + proj + bias; keep in regs + Cs ----
    float resid[24];
    #pragma unroll
    for (int i = 0; i < 24; ++i) {
        int idx = i * 256 + tid;
        int c = idx >> 6, p = idx & 63;
        float v = Cs[c*69 + p] + bproj[c] + x[((long)(b*96 + c) << 12) + n0 + p];
        resid[i] = v;
        Cs[c*69 + p] = v;
    }
    __syncthreads();
    // ---- LN2 stats ----
    {
        int p = tid >> 2, part = tid & 3, c0 = part * 24;
        float s = 0.f, ss = 0.f;
        for (int c = c0; c < c0 + 24; ++c) { float v = Cs[c*69 + p]; s += v; ss += v*v; }
        s  += __shfl_xor(s, 1);  s  += __shfl_xor(s, 2);
        ss += __shfl_xor(ss, 1); ss += __shfl_xor(ss, 2);
        float m = s * (1.f/96.f);
        float rstd = rsqrtf(ss * (1.f/96.f) - m*m + 1e-5f);
        if (part == 0) { lnm[p] = m; lnr[p] = rstd; }
    }
    __syncthreads();
    // ---- z = LN2(xh') -> As frags ----
    for (int i = 0; i < 12; ++i) {
        int idx = i * 256 + tid;
        int p = idx / 48, cp = idx % 48;
        float m = lnm[p], rs = lnr[p];
        int c = 2*cp;
        unsigned d = pack2((Cs[(c  )*69 + p] - m) * rs * g2[c  ] + b2[c  ],
                           (Cs[(c+1)*69 + p] - m) * rs * g2[c+1] + b2[c+1]);
        *(unsigned*)&As[p * 104 + 2*cp] = d;
    }
    // ---- MLP over 4 K-chunks ----
    f32x4 acc2[6];
    #pragma unroll
    for (int t = 0; t < 6; ++t) acc2[t] = (f32x4){0.f, 0.f, 0.f, 0.f};
    for (int kb = 0; kb < 4; ++kb) {
        __syncthreads();
        for (int i = 0; i < 9; ++i) {
            int idx = i * 256 + tid;
            int o = idx / 24, q4 = idx % 24;
            float4 wvv = *(const float4*)&W1[(long)(kb*96 + o)*96 + q4*4];
            uint2 d; d.x = pack2(wvv.x, wvv.y); d.y = pack2(wvv.z, wvv.w);
            *(uint2*)&Bs[o * 104 + q4*4] = d;
        }
        __syncthreads();
        f32x4 acch[6];
        #pragma unroll
        for (int t = 0; t < 6; ++t) acch[t] = (f32x4){0.f, 0.f, 0.f, 0.f};
        #pragma unroll
        for (int kc = 0; kc < 3; ++kc) {
            short8 a = *(const short8*)&As[(wv*16 + ln)*104 + kc*32 + qd*8];
            #pragma unroll
            for (int t = 0; t < 6; ++t) {
                short8 bf = *(const short8*)&Bs[(t*16 + ln)*104 + kc*32 + qd*8];
                acch[t] = __builtin_amdgcn_mfma_f32_16x16x32_bf16(a, bf, acch[t], 0, 0, 0);
            }
        }
        // gelu -> Ah A-frag layout [p][hc]
        #pragma unroll
        for (int t = 0; t < 6; ++t) {
            float bias = bm1[kb*96 + t*16 + ln];
            #pragma unroll
            for (int r = 0; r < 4; ++r) {
                float v = acch[t][r] + bias;
                v = 0.5f * v * (1.f + erff(v * 0.70710678118654752f));
                Ah[(wv*16 + qd*4 + r)*104 + t*16 + ln] = f2bf(v);
            }
        }
        __syncthreads();
        for (int i = 0; i < 9; ++i) {
            int idx = i * 256 + tid;
            int o = idx / 24, q4 = idx % 24;
            float4 wvv = *(const float4*)&W2[(long)o*384 + kb*96 + q4*4];
            uint2 d; d.x = pack2(wvv.x, wvv.y); d.y = pack2(wvv.z, wvv.w);
            *(uint2*)&Bs[o * 104 + q4*4] = d;
        }
        __syncthreads();
        #pragma unroll
        for (int kc = 0; kc < 3; ++kc) {
            short8 a = *(const short8*)&Ah[(wv*16 + ln)*104 + kc*32 + qd*8];
            #pragma unroll
            for (int t = 0; t < 6; ++t) {
                short8 bf = *(const short8*)&Bs[(t*16 + ln)*104 + kc*32 + qd*8];
                acc2[t] = __builtin_amdgcn_mfma_f32_16x16x32_bf16(a, bf, acc2[t], 0, 0, 0);
            }
        }
    }
    __syncthreads();
    #pragma unroll
    for (int t = 0; t < 6; ++t)
        #pragma unroll
        for (int r = 0; r < 4; ++r)
            Cs[(t*16 + ln)*69 + (wv*16 + qd*4 + r)] = acc2[t][r];
    __syncthreads();
    // ---- final residual + relu ----
    #pragma unroll
    for (int i = 0; i < 24; ++i) {
        int idx = i * 256 + tid;
        int c = idx >> 6, p = idx & 63;
        float v = Cs[c*69 + p] + bm2[c] + resid[i];
        Cs[c*69 + p] = fmaxf(v, 0.f);
    }
    __syncthreads();
    // ---- L2 norm over channels ----
    {
        int p = tid >> 2, part = tid & 3, c0 = part * 24;
        float ss = 0.f;
        for (int c = c0; c < c0 + 24; ++c) { float v = Cs[c*69 + p]; ss += v*v; }
        ss += __shfl_xor(ss, 1); ss += __shfl_xor(ss, 2);
        if (part == 0) lnr[p] = 1.f / fmaxf(sqrtf(ss), 1e-12f);
    }
    __syncthreads();
    // ---- write xcn position-major fp32 ----
    for (int i = 0; i < 12; ++i) {
        int idx = i * 256 + tid;
        int p = idx / 48, cp = idx % 48;
        float inv = lnr[p];
        float2 v = make_float2(Cs[(2*cp)*69 + p] * inv, Cs[(2*cp+1)*69 + p] * inv);
        *(float2*)&xcn[(bn0 + p) * 96 + 2*cp] = v;
    }
}

// ============ K6: 5x5 self-correlation (nontemporal native-vector stores) ============
__global__ __launch_bounds__(256) void k6_selfcorr(
    const float* __restrict__ xcn, float* __restrict__ out)
{
    __shared__ float xt[5 * 20 * 97];
    const int tid = threadIdx.x;
    const int wc = blockIdx.x;
    const int h  = blockIdx.y;
    const int b  = blockIdx.z;
    const int w0 = wc * 16;

    for (int i = 0; i < 38; ++i) {
        int idx = i * 256 + tid;
        if (idx < 9600) {
            int r = idx / (20 * 96);
            int rem = idx - r * (20 * 96);
            int wi = rem / 96, c = rem - wi * 96;
            int hh = h + r - 2, ww = w0 + wi - 2;
            float v = 0.f;
            if ((unsigned)hh < 64u && (unsigned)ww < 64u)
                v = xcn[(((long)b << 12) + (hh << 6) + ww) * 96 + c];
            xt[(r * 20 + wi) * 97 + c] = v;
        }
    }
    __syncthreads();
    f32x4* out4 = (f32x4*)out;
    const long ob4 = (long)b * 2457600 + (long)h * 400 + wc * 100;
    for (int i = 0; i < 38; ++i) {
        int idx = i * 256 + tid;             // 9600 float4 slots
        if (idx < 9600) {
            int c = idx / 100;
            int r4 = idx - c * 100;
            f32x4 v;
            #pragma unroll
            for (int j = 0; j < 4; ++j) {
                int r = r4 * 4 + j;
                int lw = r / 25, k = r - lw * 25;
                int ki = k / 5, kj = k - ki * 5;
                float center = xt[(42 + lw) * 97 + c];
                float neigh  = xt[(ki * 20 + lw + kj) * 97 + c];
                v[j] = center * neigh;
            }
            __builtin_nontemporal_store(v, &out4[ob4 + (long)c * 25600 + r4]);
        }
    }
}

// ============ launcher ============
extern "C" void kernel_launch(void* const* d_in, const int* in_sizes, int n_in,
                              void* d_out, int out_size, void* d_ws, size_t ws_size,
                              hipStream_t stream)
{
    const float* x     = (const float*)d_in[0];
    const float* g1    = (const float*)d_in[1];
    const float* b1    = (const float*)d_in[2];
    const float* Wqkv  = (const float*)d_in[3];
    const float* bqkv  = (const float*)d_in[4];
    const float* Wproj = (const float*)d_in[5];
    const float* bproj = (const float*)d_in[6];
    const float* g2    = (const float*)d_in[7];
    const float* b2    = (const float*)d_in[8];
    const float* W1    = (const float*)d_in[9];
    const float* bm1   = (const float*)d_in[10];
    const float* W2    = (const float*)d_in[11];
    const float* bm2   = (const float*)d_in[12];
    float* out = (float*)d_out;

    char* w = (char*)d_ws;
    unsigned* qkvt32 = (unsigned*)w;  w += (size_t)BN * 288 * 2;   // bf16 pairs
    float*    xcn    = (float*)w;

    k1_ln_qkv  <<<BN / 64, 256, 0, stream>>>(x, g1, b1, Wqkv, bqkv, qkvt32);
    k2345      <<<BN / 64, 256, 0, stream>>>(qkvt32, x, Wproj, bproj, g2, b2,
                                             W1, bm1, W2, bm2, xcn);
    k6_selfcorr<<<dim3(4, 64, 8), 256, 0, stream>>>(xcn, out);
}

// Round 6
// 421.093 us; speedup vs baseline: 1.4958x; 1.0354x over previous
//
#include <hip/hip_runtime.h>
#include <math.h>

#define NN 4096            // H*W
#define BN 32768           // B*H*W

using short8 = __attribute__((ext_vector_type(8))) short;
using f32x4  = __attribute__((ext_vector_type(4))) float;
typedef unsigned short ushort_t;

__device__ inline unsigned f2bfu(float f) {
    unsigned u = __builtin_bit_cast(unsigned, f);
    u += 0x7FFFu + ((u >> 16) & 1u);        // RNE
    return u >> 16;
}
__device__ inline ushort_t f2bf(float f) { return (ushort_t)f2bfu(f); }
__device__ inline unsigned pack2(float a, float b) { return f2bfu(a) | (f2bfu(b) << 16); }
__device__ inline float bflo(unsigned u) { return __builtin_bit_cast(float, u << 16); }
__device__ inline float bfhi(unsigned u) { return __builtin_bit_cast(float, u & 0xFFFF0000u); }

// ============ K1: LN1 + K/V GEMM only -> kvt paired-channel bf16 planes ============
// kvt u32 plane layout: plane = b*96 + kv*48 + cp (kv: 0=K,1=V), 4096 u32/plane
__global__ __launch_bounds__(256) void k1_ln_kv(
    const float* __restrict__ x, const float* __restrict__ g1, const float* __restrict__ b1,
    const float* __restrict__ Wqkv, const float* __restrict__ bqkv,
    unsigned* __restrict__ kvt32)
{
    __shared__ __align__(16) float    Cs[96 * 69];
    __shared__ __align__(16) ushort_t As[64 * 104];
    __shared__ __align__(16) ushort_t Bs[96 * 104];
    const int tid = threadIdx.x;
    const long bn0 = (long)blockIdx.x * 64;
    const int b = (int)(bn0 >> 12);
    const int n0 = (int)(bn0 & 4095);

    for (int i = 0; i < 24; ++i) {
        int idx = i * 256 + tid;
        int c = idx >> 6, p = idx & 63;
        Cs[c * 69 + p] = x[((long)(b * 96 + c) << 12) + n0 + p];
    }
    __syncthreads();
    {
        int p = tid >> 2, part = tid & 3, c0 = part * 24;
        float s = 0.f, ss = 0.f;
        for (int c = c0; c < c0 + 24; ++c) { float v = Cs[c*69 + p]; s += v; ss += v*v; }
        s  += __shfl_xor(s, 1);  s  += __shfl_xor(s, 2);
        ss += __shfl_xor(ss, 1); ss += __shfl_xor(ss, 2);
        float m = s * (1.f/96.f);
        float rstd = rsqrtf(ss * (1.f/96.f) - m*m + 1e-5f);
        for (int c = c0; c < c0 + 24; ++c)
            Cs[c*69 + p] = (Cs[c*69 + p] - m) * rstd * g1[c] + b1[c];
    }
    __syncthreads();
    for (int i = 0; i < 12; ++i) {
        int idx = i * 256 + tid;
        int p = idx / 48, cp = idx % 48;
        *(unsigned*)&As[p * 104 + 2*cp] = pack2(Cs[(2*cp)*69 + p], Cs[(2*cp+1)*69 + p]);
    }

    const int lane = tid & 63, wv = tid >> 6;
    const int ln = lane & 15, qd = lane >> 4;
    for (int kv = 0; kv < 2; ++kv) {
        __syncthreads();
        for (int i = 0; i < 9; ++i) {
            int idx = i * 256 + tid;
            int o = idx / 24, q4 = idx % 24;
            float4 wvv = *(const float4*)&Wqkv[(long)(96 + kv*96 + o)*96 + q4*4];
            uint2 d; d.x = pack2(wvv.x, wvv.y); d.y = pack2(wvv.z, wvv.w);
            *(uint2*)&Bs[o * 104 + q4*4] = d;
        }
        __syncthreads();
        f32x4 acc[6];
        #pragma unroll
        for (int t = 0; t < 6; ++t) acc[t] = (f32x4){0.f, 0.f, 0.f, 0.f};
        #pragma unroll
        for (int kc = 0; kc < 3; ++kc) {
            short8 a = *(const short8*)&As[(wv*16 + ln)*104 + kc*32 + qd*8];
            #pragma unroll
            for (int t = 0; t < 6; ++t) {
                short8 bf = *(const short8*)&Bs[(t*16 + ln)*104 + kc*32 + qd*8];
                acc[t] = __builtin_amdgcn_mfma_f32_16x16x32_bf16(a, bf, acc[t], 0, 0, 0);
            }
        }
        #pragma unroll
        for (int t = 0; t < 6; ++t)
            #pragma unroll
            for (int r = 0; r < 4; ++r)
                Cs[(t*16 + ln)*69 + (wv*16 + qd*4 + r)] = acc[t][r];
        __syncthreads();
        for (int i = 0; i < 12; ++i) {
            int idx = i * 256 + tid;
            int cp = idx / 64, p = idx % 64;
            int c = 2*cp;
            unsigned d = pack2(Cs[c*69 + p] + bqkv[96 + kv*96 + c],
                               Cs[(c+1)*69 + p] + bqkv[96 + kv*96 + c + 1]);
            kvt32[((long)(b*96 + kv*48 + cp) << 12) + n0 + p] = d;
        }
    }
}

// ============ K2345: Q-GEMM + attention + proj + resid + LN2 + MLP + resid + ReLU + L2norm ============
__global__ __launch_bounds__(256) void k2345(
    const unsigned* __restrict__ kvt32, const float* __restrict__ x,
    const float* __restrict__ g1, const float* __restrict__ b1,
    const float* __restrict__ Wqkv, const float* __restrict__ bqkv,
    const float* __restrict__ Wproj, const float* __restrict__ bproj,
    const float* __restrict__ g2, const float* __restrict__ b2,
    const float* __restrict__ W1, const float* __restrict__ bm1,
    const float* __restrict__ W2, const float* __restrict__ bm2,
    float* __restrict__ xcn)
{
    __shared__ __align__(16) float    Cs[96 * 69];     // x / xh' / acc scratch (26.5 KB)
    __shared__ __align__(16) ushort_t As[64 * 104];    // LN1 / attn-out / z frags
    __shared__ __align__(16) ushort_t Ah[64 * 104];    // Q frags / h frags
    __shared__ __align__(16) ushort_t Bs[96 * 104];    // weights
    __shared__ float lnm[64], lnr[64];
    const int tid = threadIdx.x;
    const long bn0 = (long)blockIdx.x * 64;
    const int b = (int)(bn0 >> 12);
    const int n0 = (int)(bn0 & 4095);
    const int h0 = n0 >> 6;                 // this block's image row
    const int lane = tid & 63, wv = tid >> 6;
    const int ln = lane & 15, qd = lane >> 4;

    // ---- stage x tile [c][p]; x stays in Cs until proj-residual ----
    for (int i = 0; i < 24; ++i) {
        int idx = i * 256 + tid;
        int c = idx >> 6, p = idx & 63;
        Cs[c * 69 + p] = x[((long)(b * 96 + c) << 12) + n0 + p];
    }
    __syncthreads();
    // ---- LN1 stats ----
    {
        int p = tid >> 2, part = tid & 3, c0 = part * 24;
        float s = 0.f, ss = 0.f;
        for (int c = c0; c < c0 + 24; ++c) { float v = Cs[c*69 + p]; s += v; ss += v*v; }
        s  += __shfl_xor(s, 1);  s  += __shfl_xor(s, 2);
        ss += __shfl_xor(ss, 1); ss += __shfl_xor(ss, 2);
        float m = s * (1.f/96.f);
        float rstd = rsqrtf(ss * (1.f/96.f) - m*m + 1e-5f);
        if (part == 0) { lnm[p] = m; lnr[p] = rstd; }
    }
    __syncthreads();
    // ---- LN1 -> As frags (x in Cs untouched) ----
    for (int i = 0; i < 12; ++i) {
        int idx = i * 256 + tid;
        int p = idx / 48, cp = idx % 48;
        float m = lnm[p], rs = lnr[p];
        int c = 2*cp;
        unsigned d = pack2((Cs[(c  )*69 + p] - m) * rs * g1[c  ] + b1[c  ],
                           (Cs[(c+1)*69 + p] - m) * rs * g1[c+1] + b1[c+1]);
        *(unsigned*)&As[p * 104 + 2*cp] = d;
    }
    // ---- stage Wq (rows 0..95 of Wqkv) ----
    for (int i = 0; i < 9; ++i) {
        int idx = i * 256 + tid;
        int o = idx / 24, q4 = idx % 24;
        float4 wvv = *(const float4*)&Wqkv[(long)o*96 + q4*4];
        uint2 d; d.x = pack2(wvv.x, wvv.y); d.y = pack2(wvv.z, wvv.w);
        *(uint2*)&Bs[o * 104 + q4*4] = d;
    }
    __syncthreads();
    // ---- Q MFMA -> Ah in A-frag layout [p][c], +bias ----
    {
        f32x4 acc[6];
        #pragma unroll
        for (int t = 0; t < 6; ++t) acc[t] = (f32x4){0.f, 0.f, 0.f, 0.f};
        #pragma unroll
        for (int kc = 0; kc < 3; ++kc) {
            short8 a = *(const short8*)&As[(wv*16 + ln)*104 + kc*32 + qd*8];
            #pragma unroll
            for (int t = 0; t < 6; ++t) {
                short8 bf = *(const short8*)&Bs[(t*16 + ln)*104 + kc*32 + qd*8];
                acc[t] = __builtin_amdgcn_mfma_f32_16x16x32_bf16(a, bf, acc[t], 0, 0, 0);
            }
        }
        #pragma unroll
        for (int t = 0; t < 6; ++t) {
            float bias = bqkv[t*16 + ln];
            #pragma unroll
            for (int r = 0; r < 4; ++r)
                Ah[(wv*16 + qd*4 + r)*104 + t*16 + ln] = f2bf(acc[t][r] + bias);
        }
    }
    __syncthreads();
    // ---- stage Wproj while attention runs ----
    for (int i = 0; i < 9; ++i) {
        int idx = i * 256 + tid;
        int o = idx / 24, q4 = idx % 24;
        float4 wvv = *(const float4*)&Wproj[(long)o*96 + q4*4];
        uint2 d; d.x = pack2(wvv.x, wvv.y); d.y = pack2(wvv.z, wvv.w);
        *(uint2*)&Bs[o * 104 + q4*4] = d;
    }
    // ---- attention: q from Ah (LDS), K/V from global planes -> As frags ----
    for (int it = 0; it < 2; ++it) {
        int item = it * 256 + tid;          // 64 pos x 6 (dil,head) = 384 items
        if (item < 384) {
            int p = item & 63;
            int r = item >> 6;
            int head = r & 1, di = r >> 1;
            int dil = di + 1;
            int cp0 = di*16 + head*8;       // dword-channel offset
            const unsigned* K = kvt32 + ((long)(b*96 +      cp0) << 12);
            const unsigned* V = kvt32 + ((long)(b*96 + 48 + cp0) << 12);
            int w = p;

            float q[16];
            #pragma unroll
            for (int j = 0; j < 8; ++j) {
                unsigned u = *(const unsigned*)&Ah[p * 104 + 2*(cp0 + j)];
                q[2*j] = bflo(u); q[2*j+1] = bfhi(u);
            }
            float logits[9];
            #pragma unroll
            for (int ki = 0; ki < 3; ++ki)
                #pragma unroll
                for (int kj = 0; kj < 3; ++kj) {
                    int hh = h0 + (ki-1)*dil, ww = w + (kj-1)*dil;
                    float l = 0.f;
                    if ((unsigned)hh < 64u && (unsigned)ww < 64u) {
                        int nn = (hh << 6) + ww;
                        #pragma unroll
                        for (int j = 0; j < 8; ++j) {
                            unsigned u = K[((long)j << 12) + nn];
                            l += q[2*j] * bflo(u) + q[2*j+1] * bfhi(u);
                        }
                    }
                    logits[ki*3 + kj] = l * 0.25f;
                }
            float m = logits[0];
            #pragma unroll
            for (int k = 1; k < 9; ++k) m = fmaxf(m, logits[k]);
            float e[9], s = 0.f;
            #pragma unroll
            for (int k = 0; k < 9; ++k) { e[k] = expf(logits[k] - m); s += e[k]; }
            float inv = 1.f / s;
            float o[16];
            #pragma unroll
            for (int d = 0; d < 16; ++d) o[d] = 0.f;
            #pragma unroll
            for (int ki = 0; ki < 3; ++ki)
                #pragma unroll
                for (int kj = 0; kj < 3; ++kj) {
                    int hh = h0 + (ki-1)*dil, ww = w + (kj-1)*dil;
                    if ((unsigned)hh < 64u && (unsigned)ww < 64u) {
                        int nn = (hh << 6) + ww;
                        float wgt = e[ki*3 + kj] * inv;
                        #pragma unroll
                        for (int j = 0; j < 8; ++j) {
                            unsigned u = V[((long)j << 12) + nn];
                            o[2*j]   += wgt * bflo(u);
                            o[2*j+1] += wgt * bfhi(u);
                        }
                    }
                }
            #pragma unroll
            for (int j = 0; j < 8; ++j)
                *(unsigned*)&As[p * 104 + 2*(cp0 + j)] = pack2(o[2*j], o[2*j+1]);
        }
    }
    __syncthreads();
    // ---- proj MFMA; residual in regs (x read from Cs) ----
    float resid[24];
    {
        f32x4 acc[6];
        #pragma unroll
        for (int t = 0; t < 6; ++t) acc[t] = (f32x4){0.f, 0.f, 0.f, 0.f};
        #pragma unroll
        for (int kc = 0; kc < 3; ++kc) {
            short8 a = *(const short8*)&As[(wv*16 + ln)*104 + kc*32 + qd*8];
            #pragma unroll
            for (int t = 0; t < 6; ++t) {
                short8 bf = *(const short8*)&Bs[(t*16 + ln)*104 + kc*32 + qd*8];
                acc[t] = __builtin_amdgcn_mfma_f32_16x16x32_bf16(a, bf, acc[t], 0, 0, 0);
            }
        }
        #pragma unroll
        for (int t = 0; t < 6; ++t) {
            int oc = t*16 + ln;
            float bias = bproj[oc];
            #pragma unroll
            for (int r = 0; r < 4; ++r) {
                int p = wv*16 + qd*4 + r;
                float v = acc[t][r] + bias + Cs[oc*69 + p];   // x still in Cs
                resid[t*4 + r] = v;
                Cs[oc*69 + p] = v;                             // xh' -> Cs
            }
        }
    }
    __syncthreads();
    // ---- LN2 stats ----
    {
        int p = tid >> 2, part = tid & 3, c0 = part * 24;
        float s = 0.f, ss = 0.f;
        for (int c = c0; c < c0 + 24; ++c) { float v = Cs[c*69 + p]; s += v; ss += v*v; }
        s  += __shfl_xor(s, 1);  s  += __shfl_xor(s, 2);
        ss += __shfl_xor(ss, 1); ss += __shfl_xor(ss, 2);
        float m = s * (1.f/96.f);
        float rstd = rsqrtf(ss * (1.f/96.f) - m*m + 1e-5f);
        if (part == 0) { lnm[p] = m; lnr[p] = rstd; }
    }
    __syncthreads();
    // ---- z = LN2(xh') -> As frags ----
    for (int i = 0; i < 12; ++i) {
        int idx = i * 256 + tid;
        int p = idx / 48, cp = idx % 48;
        float m = lnm[p], rs = lnr[p];
        int c = 2*cp;
        unsigned d = pack2((Cs[(c  )*69 + p] - m) * rs * g2[c  ] + b2[c  ],
                           (Cs[(c+1)*69 + p] - m) * rs * g2[c+1] + b2[c+1]);
        *(unsigned*)&As[p * 104 + 2*cp] = d;
    }
    // ---- MLP over 4 K-chunks ----
    f32x4 acc2[6];
    #pragma unroll
    for (int t = 0; t < 6; ++t) acc2[t] = (f32x4){0.f, 0.f, 0.f, 0.f};
    for (int kb = 0; kb < 4; ++kb) {
        __syncthreads();
        for (int i = 0; i < 9; ++i) {
            int idx = i * 256 + tid;
            int o = idx / 24, q4 = idx % 24;
            float4 wvv = *(const float4*)&W1[(long)(kb*96 + o)*96 + q4*4];
            uint2 d; d.x = pack2(wvv.x, wvv.y); d.y = pack2(wvv.z, wvv.w);
            *(uint2*)&Bs[o * 104 + q4*4] = d;
        }
        __syncthreads();
        f32x4 acch[6];
        #pragma unroll
        for (int t = 0; t < 6; ++t) acch[t] = (f32x4){0.f, 0.f, 0.f, 0.f};
        #pragma unroll
        for (int kc = 0; kc < 3; ++kc) {
            short8 a = *(const short8*)&As[(wv*16 + ln)*104 + kc*32 + qd*8];
            #pragma unroll
            for (int t = 0; t < 6; ++t) {
                short8 bf = *(const short8*)&Bs[(t*16 + ln)*104 + kc*32 + qd*8];
                acch[t] = __builtin_amdgcn_mfma_f32_16x16x32_bf16(a, bf, acch[t], 0, 0, 0);
            }
        }
        #pragma unroll
        for (int t = 0; t < 6; ++t) {
            float bias = bm1[kb*96 + t*16 + ln];
            #pragma unroll
            for (int r = 0; r < 4; ++r) {
                float v = acch[t][r] + bias;
                v = 0.5f * v * (1.f + erff(v * 0.70710678118654752f));
                Ah[(wv*16 + qd*4 + r)*104 + t*16 + ln] = f2bf(v);
            }
        }
        __syncthreads();
        for (int i = 0; i < 9; ++i) {
            int idx = i * 256 + tid;
            int o = idx / 24, q4 = idx % 24;
            float4 wvv = *(const float4*)&W2[(long)o*384 + kb*96 + q4*4];
            uint2 d; d.x = pack2(wvv.x, wvv.y); d.y = pack2(wvv.z, wvv.w);
            *(uint2*)&Bs[o * 104 + q4*4] = d;
        }
        __syncthreads();
        #pragma unroll
        for (int kc = 0; kc < 3; ++kc) {
            short8 a = *(const short8*)&Ah[(wv*16 + ln)*104 + kc*32 + qd*8];
            #pragma unroll
            for (int t = 0; t < 6; ++t) {
                short8 bf = *(const short8*)&Bs[(t*16 + ln)*104 + kc*32 + qd*8];
                acc2[t] = __builtin_amdgcn_mfma_f32_16x16x32_bf16(a, bf, acc2[t], 0, 0, 0);
            }
        }
    }
    __syncthreads();
    // ---- final residual (regs) + relu -> Cs ----
    #pragma unroll
    for (int t = 0; t < 6; ++t) {
        int oc = t*16 + ln;
        float bias = bm2[oc];
        #pragma unroll
        for (int r = 0; r < 4; ++r) {
            int p = wv*16 + qd*4 + r;
            float v = acc2[t][r] + bias + resid[t*4 + r];
            Cs[oc*69 + p] = fmaxf(v, 0.f);
        }
    }
    __syncthreads();
    // ---- L2 norm over channels ----
    {
        int p = tid >> 2, part = tid & 3, c0 = part * 24;
        float ss = 0.f;
        for (int c = c0; c < c0 + 24; ++c) { float v = Cs[c*69 + p]; ss += v*v; }
        ss += __shfl_xor(ss, 1); ss += __shfl_xor(ss, 2);
        if (part == 0) lnr[p] = 1.f / fmaxf(sqrtf(ss), 1e-12f);
    }
    __syncthreads();
    // ---- write xcn position-major fp32 ----
    for (int i = 0; i < 12; ++i) {
        int idx = i * 256 + tid;
        int p = idx / 48, cp = idx % 48;
        float inv = lnr[p];
        float2 v = make_float2(Cs[(2*cp)*69 + p] * inv, Cs[(2*cp+1)*69 + p] * inv);
        *(float2*)&xcn[(bn0 + p) * 96 + 2*cp] = v;
    }
}

// ============ K6: 5x5 self-correlation (nontemporal native-vector stores) ============
__global__ __launch_bounds__(256) void k6_selfcorr(
    const float* __restrict__ xcn, float* __restrict__ out)
{
    __shared__ float xt[5 * 20 * 97];
    const int tid = threadIdx.x;
    const int wc = blockIdx.x;
    const int h  = blockIdx.y;
    const int b  = blockIdx.z;
    const int w0 = wc * 16;

    for (int i = 0; i < 38; ++i) {
        int idx = i * 256 + tid;
        if (idx < 9600) {
            int r = idx / (20 * 96);
            int rem = idx - r * (20 * 96);
            int wi = rem / 96, c = rem - wi * 96;
            int hh = h + r - 2, ww = w0 + wi - 2;
            float v = 0.f;
            if ((unsigned)hh < 64u && (unsigned)ww < 64u)
                v = xcn[(((long)b << 12) + (hh << 6) + ww) * 96 + c];
            xt[(r * 20 + wi) * 97 + c] = v;
        }
    }
    __syncthreads();
    f32x4* out4 = (f32x4*)out;
    const long ob4 = (long)b * 2457600 + (long)h * 400 + wc * 100;
    for (int i = 0; i < 38; ++i) {
        int idx = i * 256 + tid;             // 9600 float4 slots
        if (idx < 9600) {
            int c = idx / 100;
            int r4 = idx - c * 100;
            f32x4 v;
            #pragma unroll
            for (int j = 0; j < 4; ++j) {
                int r = r4 * 4 + j;
                int lw = r / 25, k = r - lw * 25;
                int ki = k / 5, kj = k - ki * 5;
                float center = xt[(42 + lw) * 97 + c];
                float neigh  = xt[(ki * 20 + lw + kj) * 97 + c];
                v[j] = center * neigh;
            }
            __builtin_nontemporal_store(v, &out4[ob4 + (long)c * 25600 + r4]);
        }
    }
}

// ============ launcher ============
extern "C" void kernel_launch(void* const* d_in, const int* in_sizes, int n_in,
                              void* d_out, int out_size, void* d_ws, size_t ws_size,
                              hipStream_t stream)
{
    const float* x     = (const float*)d_in[0];
    const float* g1    = (const float*)d_in[1];
    const float* b1    = (const float*)d_in[2];
    const float* Wqkv  = (const float*)d_in[3];
    const float* bqkv  = (const float*)d_in[4];
    const float* Wproj = (const float*)d_in[5];
    const float* bproj = (const float*)d_in[6];
    const float* g2    = (const float*)d_in[7];
    const float* b2    = (const float*)d_in[8];
    const float* W1    = (const float*)d_in[9];
    const float* bm1   = (const float*)d_in[10];
    const float* W2    = (const float*)d_in[11];
    const float* bm2   = (const float*)d_in[12];
    float* out = (float*)d_out;

    char* w = (char*)d_ws;
    unsigned* kvt32 = (unsigned*)w;  w += (size_t)BN * 192 * 2;   // K,V bf16 pairs
    float*    xcn   = (float*)w;

    k1_ln_kv   <<<BN / 64, 256, 0, stream>>>(x, g1, b1, Wqkv, bqkv, kvt32);
    k2345      <<<BN / 64, 256, 0, stream>>>(kvt32, x, g1, b1, Wqkv, bqkv,
                                             Wproj, bproj, g2, b2,
                                             W1, bm1, W2, bm2, xcn);
    k6_selfcorr<<<dim3(4, 64, 8), 256, 0, stream>>>(xcn, out);
}